// Round 9
// baseline (374.040 us; speedup 1.0000x reference)
//
#include <hip/hip_runtime.h>
#include <hip/hip_bf16.h>

typedef __bf16 bf16_t;
typedef __attribute__((ext_vector_type(8))) __bf16 bf16x8;
typedef __attribute__((ext_vector_type(4))) float floatx4;

#define BM 128

enum { EPI_NONE = 0, EPI_RESID, EPI_BIAS_RELU, EPI_BIAS_RESID, EPI_QL2, EPI_PART };

__device__ __forceinline__ void gld_lds16(const bf16_t* g, bf16_t* l) {
  __builtin_amdgcn_global_load_lds(
      (__attribute__((address_space(1))) void*)(g),
      (__attribute__((address_space(3))) void*)(l), 16, 0, 0);
}

// Swizzled DMA staging: LDS slot ci=(row,cc) receives GLOBAL granule cc^(row&7).
template<int ROWS, int COLS, int NTHR>
__device__ __forceinline__ void stage_swz(const bf16_t* g, int ld, bf16_t* lds, int tid) {
  constexpr int G = COLS / 8;
  #pragma unroll
  for (int i = 0; i < ROWS * G / NTHR; ++i) {
    int ci = i * NTHR + tid;
    int row = ci / G, cc = ci % G;
    int gg = (G == 8) ? (cc ^ (row & 7)) : ((cc & 8) | ((cc & 7) ^ (row & 7)));
    gld_lds16(g + (size_t)row * ld + gg * 8, lds + ci * 8);
  }
}

// XCD-chunked bijective remap (all grids here are multiples of 8).
__device__ __forceinline__ int xcd_remap(int id, int nwg) {
  return (id & 7) * (nwg >> 3) + (id >> 3);
}

// ======== R2-proven core: 128x128 tile, BK=64, double-buffered LDS,
// prefetch issued BEFORE compute, vmcnt(0)+__syncthreads at end of step.
__device__ __forceinline__ void core128(const bf16_t* __restrict__ Ag,
                                        const bf16_t* __restrict__ Bg,
                                        int Kloop, int lda, int ldb,
                                        bf16_t* As, bf16_t* Bs,
                                        floatx4 acc[4][4]) {
  const int tid = threadIdx.x;
  const int wid = tid >> 6, lane = tid & 63;
  const int wm = (wid >> 1) * 64, wn = (wid & 1) * 64;
  const int m16 = lane & 15, quad = lane >> 4;
  const int r7 = m16 & 7;
  constexpr int BUF = BM * 64;
  stage_swz<128, 64, 256>(Ag, lda, As, tid);
  stage_swz<128, 64, 256>(Bg, ldb, Bs, tid);
  asm volatile("s_waitcnt vmcnt(0)" ::: "memory");
  __syncthreads();
  int cur = 0;
  for (int k0 = 0; k0 < Kloop; k0 += 64) {
    if (k0 + 64 < Kloop) {
      stage_swz<128, 64, 256>(Ag + k0 + 64, lda, As + (cur ^ 1) * BUF, tid);
      stage_swz<128, 64, 256>(Bg + k0 + 64, ldb, Bs + (cur ^ 1) * BUF, tid);
    }
    const bf16_t* Ab = As + cur * BUF;
    const bf16_t* Bb = Bs + cur * BUF;
    #pragma unroll
    for (int ks = 0; ks < 2; ++ks) {
      const int gi = ks * 4 + quad;
      const int slot = gi ^ r7;
      bf16x8 af[4], bfr[4];
      #pragma unroll
      for (int mt = 0; mt < 4; ++mt)
        af[mt] = *(const bf16x8*)&Ab[((wm + mt * 16 + m16) * 8 + slot) * 8];
      #pragma unroll
      for (int nt = 0; nt < 4; ++nt)
        bfr[nt] = *(const bf16x8*)&Bb[((wn + nt * 16 + m16) * 8 + slot) * 8];
      #pragma unroll
      for (int mt = 0; mt < 4; ++mt)
        #pragma unroll
        for (int nt = 0; nt < 4; ++nt)
          acc[mt][nt] = __builtin_amdgcn_mfma_f32_16x16x32_bf16(af[mt], bfr[nt], acc[mt][nt], 0, 0, 0);
    }
    asm volatile("s_waitcnt vmcnt(0)" ::: "memory");
    __syncthreads();
    cur ^= 1;
  }
}

// ======== core: 256x256 tile, BK=64, 512 thr (8 waves 2Mx4N), dbuf 128KB.
// (R6-proven 2-barrier schedule; kept for gemm_qkv)
__device__ __forceinline__ void core256sq(const bf16_t* __restrict__ Ag,
                                          const bf16_t* __restrict__ Bg,
                                          int Kloop, int lda, int ldb,
                                          bf16_t* As, bf16_t* Bs,
                                          floatx4 acc[8][4]) {
  const int tid = threadIdx.x;
  const int wid = tid >> 6, lane = tid & 63;
  const int wm = (wid >> 2) * 128;   // 2 M-halves of 128
  const int wn = (wid & 3) * 64;     // 4 N-slices of 64
  const int m16 = lane & 15, quad = lane >> 4;
  const int r7 = m16 & 7;
  constexpr int BUF = 256 * 64;
  const int NT = Kloop >> 6;
  stage_swz<256, 64, 512>(Ag, lda, As, tid);
  stage_swz<256, 64, 512>(Bg, ldb, Bs, tid);
  asm volatile("s_waitcnt vmcnt(0)" ::: "memory");
  asm volatile("s_barrier" ::: "memory");
  for (int t = 0; t < NT; ++t) {
    const int cur = t & 1;
    if (t + 1 < NT) {
      stage_swz<256, 64, 512>(Ag + (t + 1) * 64, lda, As + (cur ^ 1) * BUF, tid);
      stage_swz<256, 64, 512>(Bg + (t + 1) * 64, ldb, Bs + (cur ^ 1) * BUF, tid);
    }
    const bf16_t* Ab = As + cur * BUF;
    const bf16_t* Bb = Bs + cur * BUF;
    #pragma unroll
    for (int ks = 0; ks < 2; ++ks) {
      const int slot = (ks * 4 + quad) ^ r7;
      bf16x8 bfr[4];
      #pragma unroll
      for (int nt = 0; nt < 4; ++nt)
        bfr[nt] = *(const bf16x8*)&Bb[((wn + nt * 16 + m16) * 8 + slot) * 8];
      #pragma unroll
      for (int mh = 0; mh < 2; ++mh) {
        bf16x8 af[4];
        #pragma unroll
        for (int j = 0; j < 4; ++j)
          af[j] = *(const bf16x8*)&Ab[((wm + (mh * 4 + j) * 16 + m16) * 8 + slot) * 8];
        #pragma unroll
        for (int j = 0; j < 4; ++j)
          #pragma unroll
          for (int nt = 0; nt < 4; ++nt)
            acc[mh * 4 + j][nt] =
                __builtin_amdgcn_mfma_f32_16x16x32_bf16(af[j], bfr[nt], acc[mh * 4 + j][nt], 0, 0, 0);
      }
    }
    if (t + 1 < NT) {
      asm volatile("s_waitcnt vmcnt(0) lgkmcnt(0)" ::: "memory");
      asm volatile("s_barrier" ::: "memory");
    }
  }
}

// ======== 8-phase core (m201 template port): 256x256, BK=64, 8 waves.
// Phase order per K-tile: (ks0,A0),(ks1,A0),(ks0,A1),(ks1,A1); B frags read in
// P0/P1 and HELD in regs for P2/P3 -> A0,B0,B1 of current buffer dead after P1,
// A1 dead after P3. Tile t+2 stages into those dead regions of the CURRENT
// buffer: (t,P2): A0+B0; (t,P3): B1; (t+1,P0): A1. Every load issued >=7 phases
// before its first read. One counted vmcnt(6) per tile boundary (waits exactly
// (t+1)A1 + everything older; (t+2)'s 6 loads stay in flight). Per phase:
// ds_read -> stage-issue -> s_barrier -> setprio(1) MFMA setprio(0) -> s_barrier.
__device__ __forceinline__ void core256_8ph(const bf16_t* __restrict__ Ag,
                                            const bf16_t* __restrict__ Bg,
                                            int Kloop, int lda, int ldb,
                                            bf16_t* As, bf16_t* Bs,
                                            floatx4 acc[8][4]) {
  const int tid = threadIdx.x;
  const int wid = tid >> 6, lane = tid & 63;
  const int wmh = ((wid >> 2) & 1) * 64;  // wave row offset inside each 128-half
  const int wn = (wid & 3) * 64;
  const int m16 = lane & 15, quad = lane >> 4;
  const int r7 = m16 & 7;
  constexpr int BUF = 256 * 64;
  constexpr int HALF = 128 * 64;
  const int NT = Kloop >> 6;
  // prologue: tile0 {A0,B0,B1,A1}, tile1 {A0,B0,B1}; wait tile0 (oldest 8 of 14)
  stage_swz<128, 64, 512>(Ag, lda, As, tid);
  stage_swz<128, 64, 512>(Bg, ldb, Bs, tid);
  stage_swz<128, 64, 512>(Bg + (size_t)128 * ldb, ldb, Bs + HALF, tid);
  stage_swz<128, 64, 512>(Ag + (size_t)128 * lda, lda, As + HALF, tid);
  stage_swz<128, 64, 512>(Ag + 64, lda, As + BUF, tid);
  stage_swz<128, 64, 512>(Bg + 64, ldb, Bs + BUF, tid);
  stage_swz<128, 64, 512>(Bg + 64 + (size_t)128 * ldb, ldb, Bs + BUF + HALF, tid);
  asm volatile("s_waitcnt vmcnt(6)" ::: "memory");
  asm volatile("s_barrier" ::: "memory");
  for (int t = 0; t < NT; ++t) {
    const int bt = (t & 1) * BUF;
    const int bn = bt ^ BUF;
    const bf16_t* Ab = As + bt;
    const bf16_t* Bb = Bs + bt;
    bf16x8 bfr0[4], bfr1[4], af[4];
    // ---- P0: (ks0, A0); stage (t+1)A1 -> other buffer ----
    #pragma unroll
    for (int nt = 0; nt < 4; ++nt)
      bfr0[nt] = *(const bf16x8*)&Bb[((wn + nt * 16 + m16) * 8 + (quad ^ r7)) * 8];
    #pragma unroll
    for (int j = 0; j < 4; ++j)
      af[j] = *(const bf16x8*)&Ab[((wmh + j * 16 + m16) * 8 + (quad ^ r7)) * 8];
    if (t + 1 < NT)
      stage_swz<128, 64, 512>(Ag + (size_t)(t + 1) * 64 + (size_t)128 * lda, lda,
                              As + bn + HALF, tid);
    asm volatile("s_barrier" ::: "memory");
    __builtin_amdgcn_s_setprio(1);
    #pragma unroll
    for (int j = 0; j < 4; ++j)
      #pragma unroll
      for (int nt = 0; nt < 4; ++nt)
        acc[j][nt] = __builtin_amdgcn_mfma_f32_16x16x32_bf16(af[j], bfr0[nt], acc[j][nt], 0, 0, 0);
    __builtin_amdgcn_s_setprio(0);
    asm volatile("s_barrier" ::: "memory");
    // ---- P1: (ks1, A0) ----
    #pragma unroll
    for (int nt = 0; nt < 4; ++nt)
      bfr1[nt] = *(const bf16x8*)&Bb[((wn + nt * 16 + m16) * 8 + ((4 + quad) ^ r7)) * 8];
    #pragma unroll
    for (int j = 0; j < 4; ++j)
      af[j] = *(const bf16x8*)&Ab[((wmh + j * 16 + m16) * 8 + ((4 + quad) ^ r7)) * 8];
    asm volatile("s_barrier" ::: "memory");
    __builtin_amdgcn_s_setprio(1);
    #pragma unroll
    for (int j = 0; j < 4; ++j)
      #pragma unroll
      for (int nt = 0; nt < 4; ++nt)
        acc[j][nt] = __builtin_amdgcn_mfma_f32_16x16x32_bf16(af[j], bfr1[nt], acc[j][nt], 0, 0, 0);
    __builtin_amdgcn_s_setprio(0);
    asm volatile("s_barrier" ::: "memory");
    // ---- P2: (ks0, A1); stage (t+2){A0,B0} into CURRENT buffer's dead regions ----
    #pragma unroll
    for (int j = 0; j < 4; ++j)
      af[j] = *(const bf16x8*)&Ab[((128 + wmh + j * 16 + m16) * 8 + (quad ^ r7)) * 8];
    if (t + 2 < NT) {
      stage_swz<128, 64, 512>(Ag + (size_t)(t + 2) * 64, lda, As + bt, tid);
      stage_swz<128, 64, 512>(Bg + (size_t)(t + 2) * 64, ldb, Bs + bt, tid);
    }
    asm volatile("s_barrier" ::: "memory");
    __builtin_amdgcn_s_setprio(1);
    #pragma unroll
    for (int j = 0; j < 4; ++j)
      #pragma unroll
      for (int nt = 0; nt < 4; ++nt)
        acc[4 + j][nt] = __builtin_amdgcn_mfma_f32_16x16x32_bf16(af[j], bfr0[nt], acc[4 + j][nt], 0, 0, 0);
    __builtin_amdgcn_s_setprio(0);
    asm volatile("s_barrier" ::: "memory");
    // ---- P3: (ks1, A1); stage (t+2)B1 ----
    #pragma unroll
    for (int j = 0; j < 4; ++j)
      af[j] = *(const bf16x8*)&Ab[((128 + wmh + j * 16 + m16) * 8 + ((4 + quad) ^ r7)) * 8];
    if (t + 2 < NT)
      stage_swz<128, 64, 512>(Bg + (size_t)(t + 2) * 64 + (size_t)128 * ldb, ldb,
                              Bs + bt + HALF, tid);
    asm volatile("s_barrier" ::: "memory");
    __builtin_amdgcn_s_setprio(1);
    #pragma unroll
    for (int j = 0; j < 4; ++j)
      #pragma unroll
      for (int nt = 0; nt < 4; ++nt)
        acc[4 + j][nt] = __builtin_amdgcn_mfma_f32_16x16x32_bf16(af[j], bfr1[nt], acc[4 + j][nt], 0, 0, 0);
    __builtin_amdgcn_s_setprio(0);
    // ---- boundary: counted wait, (t+2)'s loads stay in flight ----
    if (t + 1 < NT) {
      if (t + 2 < NT) asm volatile("s_waitcnt vmcnt(6)" ::: "memory");
      else            asm volatile("s_waitcnt vmcnt(0)" ::: "memory");
    }
    asm volatile("s_barrier" ::: "memory");
  }
}

// ---- 256x256 bf16 GEMM (W1: bias+relu); 8-phase core; XCD-chunked + GROUP_M=8 ----
template<int EPI>
__global__ __launch_bounds__(512)
void gemm256(const bf16_t* __restrict__ A, const bf16_t* __restrict__ B,
             bf16_t* __restrict__ C, const float* __restrict__ bias,
             int N, int K, int mblocks, int nblocks) {
  __shared__ bf16_t As[2 * 256 * 64];   // 64 KB
  __shared__ bf16_t Bs[2 * 256 * 64];   // 64 KB
  const int tid = threadIdx.x;
  const int wid = tid >> 6, lane = tid & 63;
  const int wmh = ((wid >> 2) & 1) * 64, wn = (wid & 3) * 64;
  const int m16 = lane & 15, quad = lane >> 4;
  const int id = xcd_remap(blockIdx.x, gridDim.x);
  const int per_group = 8 * nblocks;
  const int grp = id / per_group, rem = id % per_group;
  const int m0 = (grp * 8 + (rem & 7)) * 256;
  const int n0 = (rem >> 3) * 256;
  floatx4 acc[8][4];
  const floatx4 vzero = {0.f, 0.f, 0.f, 0.f};
  #pragma unroll
  for (int mt = 0; mt < 8; ++mt)
    #pragma unroll
    for (int nt = 0; nt < 4; ++nt) acc[mt][nt] = vzero;
  core256_8ph(A + (size_t)m0 * K, B + (size_t)n0 * K, K, K, K, As, Bs, acc);
  // 8-phase layout: acc[mh*4+j] covers rows mh*128 + wmh + j*16 (+quad*4+r)
  #pragma unroll
  for (int mh = 0; mh < 2; ++mh)
    #pragma unroll
    for (int j = 0; j < 4; ++j)
      #pragma unroll
      for (int nt = 0; nt < 4; ++nt) {
        const int gcol = n0 + wn + nt * 16 + m16;
        float bv = (EPI == EPI_BIAS_RELU) ? bias[gcol] : 0.f;
        #pragma unroll
        for (int r = 0; r < 4; ++r) {
          const int grow = m0 + mh * 128 + wmh + j * 16 + quad * 4 + r;
          float v = acc[mh * 4 + j][nt][r];
          if (EPI == EPI_BIAS_RELU) { v += bv; v = fmaxf(v, 0.f); }
          C[(size_t)grow * N + gcol] = (bf16_t)v;
        }
      }
}

// ---- fused QKV on 256x256 core (R6-proven); Q scaled 1/8; V transposed ----
__global__ __launch_bounds__(512)
void gemm_qkv(const bf16_t* __restrict__ X, const bf16_t* __restrict__ Wb,
              bf16_t* __restrict__ Qo, bf16_t* __restrict__ Ko, bf16_t* __restrict__ Vt) {
  __shared__ bf16_t As[2 * 256 * 64];
  __shared__ bf16_t Bs[2 * 256 * 64];
  const int tid = threadIdx.x;
  const int wid = tid >> 6, lane = tid & 63;
  const int wm = (wid >> 2) * 128, wn = (wid & 3) * 64;
  const int m16 = lane & 15, quad = lane >> 4;
  const int id = xcd_remap(blockIdx.x, gridDim.x);
  const int per_group = 8 * 12;            // GROUP_M=8 x (4 nblocks * 3 sel)
  const int grp = id / per_group, rem = id % per_group;
  const int m0 = (grp * 8 + (rem & 7)) * 256;
  const int nall = rem >> 3;               // 0..11
  const int n0 = (nall & 3) * 256;
  const int sel = nall >> 2;
  const bf16_t* B = Wb + (size_t)sel * 1024 * 1024;
  floatx4 acc[8][4];
  const floatx4 vzero = {0.f, 0.f, 0.f, 0.f};
  #pragma unroll
  for (int mt = 0; mt < 8; ++mt)
    #pragma unroll
    for (int nt = 0; nt < 4; ++nt) acc[mt][nt] = vzero;
  core256sq(X + (size_t)m0 * 1024, B + (size_t)n0 * 1024, 1024, 1024, 1024, As, Bs, acc);
  if (sel < 2) {
    bf16_t* C = sel ? Ko : Qo;
    const float sc = sel ? 1.f : 0.125f;
    #pragma unroll
    for (int mt = 0; mt < 8; ++mt)
      #pragma unroll
      for (int nt = 0; nt < 4; ++nt) {
        const int gcol = n0 + wn + nt * 16 + m16;
        #pragma unroll
        for (int r = 0; r < 4; ++r) {
          const int grow = m0 + wm + mt * 16 + quad * 4 + r;
          C[(size_t)grow * 1024 + gcol] = (bf16_t)(acc[mt][nt][r] * sc);
        }
      }
  } else {
    #pragma unroll
    for (int mt = 0; mt < 8; ++mt) {
      const int grow0 = m0 + wm + mt * 16 + quad * 4;
      const int b = grow0 >> 10, s = grow0 & 1023;
      #pragma unroll
      for (int nt = 0; nt < 4; ++nt) {
        const int gcol = n0 + wn + nt * 16 + m16;
        const int h = gcol >> 6, d = gcol & 63;
        #pragma unroll
        for (int r = 0; r < 4; ++r)
          Vt[(((size_t)b * 16 + h) * 64 + d) * 1024 + s + r] = (bf16_t)acc[mt][nt][r];
      }
    }
  }
}

// ---- 128x128 split-K=2; R2-proven core; XCD-chunked, GROUP_M=8 (Wo, W2) ----
__global__ __launch_bounds__(256)
void gemm128_sk(const bf16_t* __restrict__ A, const bf16_t* __restrict__ B,
                bf16_t* __restrict__ p0, bf16_t* __restrict__ p1,
                int N, int K, int ldb, int mblocks, int nblocks) {
  __shared__ bf16_t As[2 * BM * 64];
  __shared__ bf16_t Bs[2 * BM * 64];
  const int tid = threadIdx.x;
  const int wid = tid >> 6, lane = tid & 63;
  const int wm = (wid >> 1) * 64, wn = (wid & 1) * 64;
  const int m16 = lane & 15, quad = lane >> 4;
  const int id = xcd_remap(blockIdx.x, gridDim.x);
  const int per_kh = mblocks * nblocks;
  const int kh = id / per_kh;
  const int rem2 = id % per_kh;
  const int per_group = 8 * nblocks;
  const int grp = rem2 / per_group, rem = rem2 % per_group;
  const int m0 = (grp * 8 + (rem & 7)) * BM;
  const int n0 = (rem >> 3) * BM;
  const int Keff = K / 2;
  floatx4 acc[4][4];
  const floatx4 vzero = {0.f, 0.f, 0.f, 0.f};
  #pragma unroll
  for (int mt = 0; mt < 4; ++mt)
    #pragma unroll
    for (int nt = 0; nt < 4; ++nt) acc[mt][nt] = vzero;
  core128(A + (size_t)m0 * K + (size_t)kh * Keff,
          B + (size_t)n0 * ldb + (size_t)kh * Keff, Keff, K, ldb, As, Bs, acc);
  bf16_t* Cp = kh ? p1 : p0;
  #pragma unroll
  for (int mt = 0; mt < 4; ++mt)
    #pragma unroll
    for (int nt = 0; nt < 4; ++nt) {
      const int gcol = n0 + wn + nt * 16 + m16;
      #pragma unroll
      for (int r = 0; r < 4; ++r) {
        const int grow = m0 + wm + mt * 16 + quad * 4 + r;
        Cp[(size_t)grow * N + gcol] = (bf16_t)acc[mt][nt][r];
      }
    }
}

// ======== ql2 final GEMM: 128x64 tile, BK=64, R2-pipelined, 512 blocks (2/CU),
// 48 KB LDS; QL2 epilogue (bias + z-dot), fp32 out ========
__global__ __launch_bounds__(256)
void gemm64p(const bf16_t* __restrict__ A, const bf16_t* __restrict__ B,
             float* __restrict__ C, const float* __restrict__ bias,
             const bf16_t* __restrict__ z, const float* __restrict__ zw) {
  __shared__ bf16_t As[2 * 128 * 64];   // 32 KB
  __shared__ bf16_t Bs[2 * 64 * 64];    // 16 KB
  const int tid = threadIdx.x;
  const int wid = tid >> 6, lane = tid & 63;
  const int wm = (wid >> 1) * 64, wn = (wid & 1) * 32;
  const int m16 = lane & 15, quad = lane >> 4;
  const int r7 = m16 & 7;
  const int id = xcd_remap(blockIdx.x, gridDim.x);
  const int per_group = 8 * 16;   // GROUP_M=8 x 16 nblocks(64-wide)
  const int grp = id / per_group, rem = id % per_group;
  const int m0 = (grp * 8 + (rem & 7)) * 128;
  const int n0 = (rem >> 3) * 64;
  // B row n = output col n: ql2wb[n*1032 + 8 + k] (first 8 are z-weights)
  const bf16_t* Ag = A + (size_t)m0 * 1024;
  const bf16_t* Bg = B + (size_t)n0 * 1032 + 8;
  constexpr int ABUF = 128 * 64, BBUF = 64 * 64;
  floatx4 acc[4][2];
  const floatx4 vzero = {0.f, 0.f, 0.f, 0.f};
  #pragma unroll
  for (int mt = 0; mt < 4; ++mt)
    #pragma unroll
    for (int nt = 0; nt < 2; ++nt) acc[mt][nt] = vzero;
  stage_swz<128, 64, 256>(Ag, 1024, As, tid);
  stage_swz<64, 64, 256>(Bg, 1032, Bs, tid);
  asm volatile("s_waitcnt vmcnt(0)" ::: "memory");
  __syncthreads();
  int cur = 0;
  for (int k0 = 0; k0 < 1024; k0 += 64) {
    if (k0 + 64 < 1024) {
      stage_swz<128, 64, 256>(Ag + k0 + 64, 1024, As + (cur ^ 1) * ABUF, tid);
      stage_swz<64, 64, 256>(Bg + k0 + 64, 1032, Bs + (cur ^ 1) * BBUF, tid);
    }
    const bf16_t* Ab = As + cur * ABUF;
    const bf16_t* Bb = Bs + cur * BBUF;
    #pragma unroll
    for (int ks = 0; ks < 2; ++ks) {
      const int slot = (ks * 4 + quad) ^ r7;
      bf16x8 af[4], bfr[2];
      #pragma unroll
      for (int mt = 0; mt < 4; ++mt)
        af[mt] = *(const bf16x8*)&Ab[((wm + mt * 16 + m16) * 8 + slot) * 8];
      #pragma unroll
      for (int nt = 0; nt < 2; ++nt)
        bfr[nt] = *(const bf16x8*)&Bb[((wn + nt * 16 + m16) * 8 + slot) * 8];
      #pragma unroll
      for (int mt = 0; mt < 4; ++mt)
        #pragma unroll
        for (int nt = 0; nt < 2; ++nt)
          acc[mt][nt] = __builtin_amdgcn_mfma_f32_16x16x32_bf16(af[mt], bfr[nt], acc[mt][nt], 0, 0, 0);
    }
    asm volatile("s_waitcnt vmcnt(0)" ::: "memory");
    __syncthreads();
    cur ^= 1;
  }
  #pragma unroll
  for (int mt = 0; mt < 4; ++mt)
    #pragma unroll
    for (int nt = 0; nt < 2; ++nt) {
      const int gcol = n0 + wn + nt * 16 + m16;
      const float bv = bias[gcol];
      #pragma unroll
      for (int r = 0; r < 4; ++r) {
        const int grow = m0 + wm + mt * 16 + quad * 4 + r;
        float s = 0.f;
        #pragma unroll
        for (int u = 0; u < 8; ++u)
          s += (float)z[(size_t)grow * 8 + u] * zw[(size_t)gcol * 1032 + u];
        C[(size_t)grow * 1024 + gcol] = acc[mt][nt][r] + bv + s;
      }
    }
}

// ======== flash attention (R6-proven): DMA K/V, 2-deep, XCD-chunked heads ========
__global__ __launch_bounds__(256)
void attn_kernel(const bf16_t* __restrict__ Q, const bf16_t* __restrict__ Kb,
                 const bf16_t* __restrict__ Vt, bf16_t* __restrict__ O) {
  __shared__ bf16_t Qs[64 * 64];        // 8 KB
  __shared__ bf16_t Ks[2][128 * 64];    // 32 KB (double-buffered)
  __shared__ bf16_t Vs[64 * 128];       // 16 KB
  __shared__ bf16_t Ps[4][16 * 128];    // 16 KB
  const int tid = threadIdx.x;
  const int wid = tid >> 6, lane = tid & 63;
  const int m16 = lane & 15, quad = lane >> 4;
  const int id = blockIdx.x;
  const int bh = (id & 7) * 8 + ((id >> 3) & 7);
  const int qt = id >> 6;
  const int b = bh >> 4, h = bh & 15;
  const size_t qbase = ((size_t)(b * 1024 + qt * 64)) * 1024 + h * 64;
  const size_t kbase = ((size_t)(b * 1024)) * 1024 + h * 64;
  const size_t vbase = ((size_t)bh * 64) * 1024;
  #pragma unroll
  for (int i = 0; i < 2; ++i) {
    int ci = i * 256 + tid;
    int row = ci >> 3, cc = ci & 7;
    *(bf16x8*)&Qs[row * 64 + ((cc ^ (row & 7)) * 8)] =
        *(const bf16x8*)&Q[qbase + (size_t)row * 1024 + cc * 8];
  }
  stage_swz<128, 64, 256>(Kb + kbase, 1024, Ks[0], tid);
  asm volatile("s_waitcnt vmcnt(0)" ::: "memory");
  __syncthreads();
  const int qm = wid * 16 + m16;
  bf16x8 qf0 = *(const bf16x8*)&Qs[qm * 64 + ((quad ^ (qm & 7)) * 8)];
  bf16x8 qf1 = *(const bf16x8*)&Qs[qm * 64 + (((4 + quad) ^ (qm & 7)) * 8)];
  floatx4 oacc[4];
  float rs[4];
  const floatx4 vzero = {0.f, 0.f, 0.f, 0.f};
  #pragma unroll
  for (int dt = 0; dt < 4; ++dt) oacc[dt] = vzero;
  #pragma unroll
  for (int r = 0; r < 4; ++r) rs[r] = 0.f;
  for (int kt = 0; kt < 8; ++kt) {
    stage_swz<64, 128, 256>(Vt + vbase + kt * 128, 1024, Vs, tid);
    if (kt < 7)
      stage_swz<128, 64, 256>(Kb + kbase + (size_t)(kt + 1) * 128 * 1024, 1024, Ks[(kt + 1) & 1], tid);
    const bf16_t* Kc = Ks[kt & 1];
    floatx4 sa[8];
    #pragma unroll
    for (int nt = 0; nt < 8; ++nt) sa[nt] = vzero;
    #pragma unroll
    for (int nt = 0; nt < 8; ++nt) {
      const int n = nt * 16 + m16;
      bf16x8 kf0 = *(const bf16x8*)&Kc[n * 64 + ((quad ^ (n & 7)) * 8)];
      bf16x8 kf1 = *(const bf16x8*)&Kc[n * 64 + (((4 + quad) ^ (n & 7)) * 8)];
      sa[nt] = __builtin_amdgcn_mfma_f32_16x16x32_bf16(qf0, kf0, sa[nt], 0, 0, 0);
      sa[nt] = __builtin_amdgcn_mfma_f32_16x16x32_bf16(qf1, kf1, sa[nt], 0, 0, 0);
    }
    #pragma unroll
    for (int nt = 0; nt < 8; ++nt)
      #pragma unroll
      for (int r = 0; r < 4; ++r) {
        float pv = __expf(sa[nt][r]);
        rs[r] += pv;
        const int prow = quad * 4 + r;
        const int g = nt * 2 + (m16 >> 3);
        const int gs = (g & 8) | ((g & 7) ^ (prow & 7));
        Ps[wid][prow * 128 + gs * 8 + (m16 & 7)] = (bf16_t)pv;
      }
    asm volatile("s_waitcnt vmcnt(0)" ::: "memory");
    __syncthreads();
    bf16x8 pf[4];
    #pragma unroll
    for (int ksub = 0; ksub < 4; ++ksub) {
      const int g = ksub * 4 + quad;
      const int gs = (g & 8) | ((g & 7) ^ (m16 & 7));
      pf[ksub] = *(const bf16x8*)&Ps[wid][m16 * 128 + gs * 8];
    }
    #pragma unroll
    for (int dt = 0; dt < 4; ++dt) {
      const int n = dt * 16 + m16;
      #pragma unroll
      for (int ksub = 0; ksub < 4; ++ksub) {
        const int g = ksub * 4 + quad;
        const int gs = (g & 8) | ((g & 7) ^ (n & 7));
        bf16x8 vf = *(const bf16x8*)&Vs[n * 128 + gs * 8];
        oacc[dt] = __builtin_amdgcn_mfma_f32_16x16x32_bf16(pf[ksub], vf, oacc[dt], 0, 0, 0);
      }
    }
    __syncthreads();
  }
  #pragma unroll
  for (int r = 0; r < 4; ++r) {
    rs[r] += __shfl_xor(rs[r], 1);
    rs[r] += __shfl_xor(rs[r], 2);
    rs[r] += __shfl_xor(rs[r], 4);
    rs[r] += __shfl_xor(rs[r], 8);
  }
  const size_t obase = ((size_t)(b * 1024 + qt * 64 + wid * 16)) * 1024 + h * 64;
  #pragma unroll
  for (int dt = 0; dt < 4; ++dt)
    #pragma unroll
    for (int r = 0; r < 4; ++r)
      O[obase + (size_t)(quad * 4 + r) * 1024 + dt * 16 + m16] = (bf16_t)(oacc[dt][r] / rs[r]);
}

// ---------------- segmented fp32 -> bf16 conversion ----------------
struct Segs {
  const float* s[5];
  bf16_t* d[5];
  int n8[5];
};
__global__ __launch_bounds__(256)
void conv_multi(Segs sg) {
  const int zz = blockIdx.z;
  const float* in = sg.s[zz];
  bf16_t* out = sg.d[zz];
  const int n8 = sg.n8[zz];
  for (int i = blockIdx.x * 256 + threadIdx.x; i < n8; i += gridDim.x * 256) {
    const float* p = in + (size_t)i * 8;
    floatx4 a = *(const floatx4*)p;
    floatx4 b = *(const floatx4*)(p + 4);
    bf16x8 o;
    #pragma unroll
    for (int j = 0; j < 4; ++j) { o[j] = (bf16_t)a[j]; o[4 + j] = (bf16_t)b[j]; }
    *(bf16x8*)(out + (size_t)i * 8) = o;
  }
}

// ---------------- LN1 with split-K combine: in = p0 + p1 + resid ----------------
__global__ __launch_bounds__(256)
void ln_combine(const bf16_t* __restrict__ p0, const bf16_t* __restrict__ p1,
                const bf16_t* __restrict__ resid,
                const float* __restrict__ g, const float* __restrict__ b,
                bf16_t* __restrict__ out) {
  const int row = blockIdx.x * 4 + (threadIdx.x >> 6);
  const int lane = threadIdx.x & 63;
  const size_t base = (size_t)row * 1024 + lane * 16;
  bf16x8 a0 = *(const bf16x8*)&p0[base];
  bf16x8 a1 = *(const bf16x8*)&p0[base + 8];
  bf16x8 b0 = *(const bf16x8*)&p1[base];
  bf16x8 b1 = *(const bf16x8*)&p1[base + 8];
  bf16x8 c0 = *(const bf16x8*)&resid[base];
  bf16x8 c1 = *(const bf16x8*)&resid[base + 8];
  float f[16];
  #pragma unroll
  for (int j = 0; j < 8; ++j) {
    f[j]     = (float)a0[j] + (float)b0[j] + (float)c0[j];
    f[8 + j] = (float)a1[j] + (float)b1[j] + (float)c1[j];
  }
  float s = 0.f, ss = 0.f;
  #pragma unroll
  for (int j = 0; j < 16; ++j) { s += f[j]; ss += f[j] * f[j]; }
  #pragma unroll
  for (int off = 1; off < 64; off <<= 1) { s += __shfl_xor(s, off); ss += __shfl_xor(ss, off); }
  const float m = s * (1.f / 1024.f);
  const float inv_sd = rsqrtf(ss * (1.f / 1024.f) - m * m + 1e-5f);
  const float* gp = g + lane * 16;
  const float* bp = b + lane * 16;
  bf16x8 o0, o1;
  #pragma unroll
  for (int j = 0; j < 8; ++j) o0[j] = (bf16_t)((f[j] - m) * inv_sd * gp[j] + bp[j]);
  #pragma unroll
  for (int j = 0; j < 8; ++j) o1[j] = (bf16_t)((f[8 + j] - m) * inv_sd * gp[8 + j] + bp[8 + j]);
  *(bf16x8*)&out[base] = o0;
  *(bf16x8*)&out[base + 8] = o1;
}

// ---- fused: (W2 combine + b2 + resid) -> LN2 -> x2; quantum -> z; ql2w conv ----
__global__ __launch_bounds__(256)
void ln2_quantum(const bf16_t* __restrict__ p0, const bf16_t* __restrict__ p1,
                 const bf16_t* __restrict__ resid, const float* __restrict__ bias,
                 const float* __restrict__ g, const float* __restrict__ b,
                 bf16_t* __restrict__ x2,
                 const float* __restrict__ qw1, const float* __restrict__ qb1,
                 const float* __restrict__ qwt, bf16_t* __restrict__ zout,
                 const float* __restrict__ ql2w, bf16_t* __restrict__ ql2wb) {
  if (blockIdx.z == 1) {
    const int n8 = 1024 * 1032 / 8;
    for (int i = blockIdx.x * 256 + threadIdx.x; i < n8; i += gridDim.x * 256) {
      const float* p = ql2w + (size_t)i * 8;
      floatx4 a = *(const floatx4*)p;
      floatx4 bb = *(const floatx4*)(p + 4);
      bf16x8 o;
      #pragma unroll
      for (int j = 0; j < 4; ++j) { o[j] = (bf16_t)a[j]; o[4 + j] = (bf16_t)bb[j]; }
      *(bf16x8*)(ql2wb + (size_t)i * 8) = o;
    }
    return;
  }
  const int row = blockIdx.x * 4 + (threadIdx.x >> 6);
  const int lane = threadIdx.x & 63;
  const size_t base = (size_t)row * 1024 + lane * 16;
  bf16x8 a0 = *(const bf16x8*)&p0[base];
  bf16x8 a1 = *(const bf16x8*)&p0[base + 8];
  bf16x8 b0 = *(const bf16x8*)&p1[base];
  bf16x8 b1 = *(const bf16x8*)&p1[base + 8];
  bf16x8 c0 = *(const bf16x8*)&resid[base];
  bf16x8 c1 = *(const bf16x8*)&resid[base + 8];
  const float* bsp = bias + lane * 16;
  float f[16];
  #pragma unroll
  for (int j = 0; j < 8; ++j) {
    f[j]     = (float)a0[j] + (float)b0[j] + (float)c0[j] + bsp[j];
    f[8 + j] = (float)a1[j] + (float)b1[j] + (float)c1[j] + bsp[8 + j];
  }
  float s = 0.f, ss = 0.f;
  #pragma unroll
  for (int j = 0; j < 16; ++j) { s += f[j]; ss += f[j] * f[j]; }
  #pragma unroll
  for (int off = 1; off < 64; off <<= 1) { s += __shfl_xor(s, off); ss += __shfl_xor(ss, off); }
  const float m = s * (1.f / 1024.f);
  const float inv_sd = rsqrtf(ss * (1.f / 1024.f) - m * m + 1e-5f);
  const float* gp = g + lane * 16;
  const float* bp = b + lane * 16;
  bf16x8 o0, o1;
  #pragma unroll
  for (int j = 0; j < 8; ++j) o0[j] = (bf16_t)((f[j] - m) * inv_sd * gp[j] + bp[j]);
  #pragma unroll
  for (int j = 0; j < 8; ++j) o1[j] = (bf16_t)((f[8 + j] - m) * inv_sd * gp[8 + j] + bp[8 + j]);
  *(bf16x8*)&x2[base] = o0;
  *(bf16x8*)&x2[base + 8] = o1;
  float th[8];
  #pragma unroll
  for (int qq = 0; qq < 8; ++qq) {
    const float* wp = qw1 + (size_t)qq * 1024 + lane * 16;
    float sdot = 0.f;
    #pragma unroll
    for (int j = 0; j < 8; ++j)
      sdot += (float)o0[j] * wp[j] + (float)o1[j] * wp[8 + j];
    #pragma unroll
    for (int off = 1; off < 64; off <<= 1) sdot += __shfl_xor(sdot, off);
    th[qq] = sdot + qb1[qq] + qwt[qq];
  }
  if (lane == 0) {
    float c[8];
    #pragma unroll
    for (int qq = 0; qq < 8; ++qq) c[qq] = cosf(th[qq]);
    float z0 = 1.f;
    #pragma unroll
    for (int u = 1; u < 8; ++u) z0 *= c[u];
    zout[(size_t)row * 8 + 0] = (bf16_t)z0;
    float pp = c[0];
    #pragma unroll
    for (int w = 1; w < 8; ++w) { pp *= c[w]; zout[(size_t)row * 8 + w] = (bf16_t)pp; }
  }
}

extern "C" void kernel_launch(void* const* d_in, const int* in_sizes, int n_in,
                              void* d_out, int out_size, void* d_ws, size_t ws_size,
                              hipStream_t stream) {
  const float* x    = (const float*)d_in[0];
  const float* Wq   = (const float*)d_in[1];
  const float* Wk   = (const float*)d_in[2];
  const float* Wv   = (const float*)d_in[3];
  const float* Wo   = (const float*)d_in[4];
  const float* ln1g = (const float*)d_in[5];
  const float* ln1b = (const float*)d_in[6];
  const float* W1   = (const float*)d_in[7];
  const float* b1   = (const float*)d_in[8];
  const float* W2   = (const float*)d_in[9];
  const float* b2   = (const float*)d_in[10];
  const float* ln2g = (const float*)d_in[11];
  const float* ln2b = (const float*)d_in[12];
  const float* qw1  = (const float*)d_in[13];
  const float* qb1  = (const float*)d_in[14];
  const float* qwt  = (const float*)d_in[15];
  const float* ql2w = (const float*)d_in[16];
  const float* ql2b = (const float*)d_in[17];
  bf16_t* ws = (bf16_t*)d_ws;

  const size_t T = (size_t)4096 * 1024;
  const size_t M1 = (size_t)1024 * 1024;
  bf16_t* outlo = (bf16_t*)d_out;
  bf16_t* outhi = outlo + T;

  bf16_t* xb    = ws;            // x bf16; resid for LN1; then W2 partial p0
  bf16_t* kb    = ws + T;        // K; Wo partial p1; then w2b; then z
  bf16_t* vt    = ws + 2 * T;    // V^T; then w1b; then W2 partial p1 / x2
  bf16_t* ff    = ws + 3 * T;    // wqkvb+wob; then FFN hidden; then ql2wb
  bf16_t* wqkvb = ff;
  bf16_t* wob   = ff + 3 * M1;
  bf16_t* w1b   = vt;
  bf16_t* w2b   = kb;
  bf16_t* ql2wb = ff;
  bf16_t* q     = outlo;
  bf16_t* o     = outhi;
  bf16_t* x1    = outhi;         // LN1 out (o dead)
  bf16_t* x2    = vt;            // LN2 out (in-place over W2 p1)
  bf16_t* z     = kb;

  {
    Segs sg;
    sg.s[0] = x;  sg.d[0] = xb;            sg.n8[0] = (int)(T / 8);
    sg.s[1] = Wq; sg.d[1] = wqkvb;         sg.n8[1] = (int)(M1 / 8);
    sg.s[2] = Wk; sg.d[2] = wqkvb + M1;    sg.n8[2] = (int)(M1 / 8);
    sg.s[3] = Wv; sg.d[3] = wqkvb + 2*M1;  sg.n8[3] = (int)(M1 / 8);
    sg.s[4] = Wo; sg.d[4] = wob;           sg.n8[4] = (int)(M1 / 8);
    conv_multi<<<dim3(512, 1, 5), 256, 0, stream>>>(sg);
  }
  gemm_qkv<<<192, 512, 0, stream>>>(xb, wqkvb, q, kb, vt);
  attn_kernel<<<1024, 256, 0, stream>>>(q, kb, vt, o);
  // Wo split-K=2 on 128x128 tile: partials outlo (q dead) + kb (K dead).
  gemm128_sk<<<512, 256, 0, stream>>>(o, wob, outlo, kb, 1024, 1024, 1024, 32, 8);
  ln_combine<<<1024, 256, 0, stream>>>(outlo, kb, xb, ln1g, ln1b, x1);
  {
    Segs sg;
    sg.s[0] = W1; sg.d[0] = w1b; sg.n8[0] = (int)(T / 8);
    sg.s[1] = W2; sg.d[1] = w2b; sg.n8[1] = (int)(T / 8);
    sg.s[2] = nullptr; sg.d[2] = nullptr; sg.n8[2] = 0;
    sg.s[3] = nullptr; sg.d[3] = nullptr; sg.n8[3] = 0;
    sg.s[4] = nullptr; sg.d[4] = nullptr; sg.n8[4] = 0;
    conv_multi<<<dim3(1024, 1, 2), 256, 0, stream>>>(sg);
  }
  gemm256<EPI_BIAS_RELU><<<256, 512, 0, stream>>>(x1, w1b, ff, b1, 4096, 1024, 16, 16);
  // W2 split-K=2 on 128x128 tile: partials xb (x dead) + vt (w1b dead).
  gemm128_sk<<<512, 256, 0, stream>>>(ff, w2b, xb, vt, 1024, 4096, 4096, 32, 8);
  ln2_quantum<<<dim3(1024, 1, 2), 256, 0, stream>>>(
      xb, vt, x1, b2, ln2g, ln2b, x2, qw1, qb1, qwt, z, ql2w, ql2wb);
  gemm64p<<<512, 256, 0, stream>>>(x2, ql2wb, (float*)d_out, ql2b, z, ql2w);
}

// Round 10
// 369.092 us; speedup vs baseline: 1.0134x; 1.0134x over previous
//
#include <hip/hip_runtime.h>
#include <hip/hip_bf16.h>

typedef __bf16 bf16_t;
typedef __attribute__((ext_vector_type(8))) __bf16 bf16x8;
typedef __attribute__((ext_vector_type(4))) float floatx4;

#define BM 128

enum { EPI_NONE = 0, EPI_RESID, EPI_BIAS_RELU, EPI_BIAS_RESID, EPI_QL2, EPI_PART };

__device__ __forceinline__ void gld_lds16(const bf16_t* g, bf16_t* l) {
  __builtin_amdgcn_global_load_lds(
      (__attribute__((address_space(1))) void*)(g),
      (__attribute__((address_space(3))) void*)(l), 16, 0, 0);
}

// Swizzled DMA staging: LDS slot ci=(row,cc) receives GLOBAL granule cc^(row&7).
template<int ROWS, int COLS, int NTHR>
__device__ __forceinline__ void stage_swz(const bf16_t* g, int ld, bf16_t* lds, int tid) {
  constexpr int G = COLS / 8;
  #pragma unroll
  for (int i = 0; i < ROWS * G / NTHR; ++i) {
    int ci = i * NTHR + tid;
    int row = ci / G, cc = ci % G;
    int gg = (G == 8) ? (cc ^ (row & 7)) : ((cc & 8) | ((cc & 7) ^ (row & 7)));
    gld_lds16(g + (size_t)row * ld + gg * 8, lds + ci * 8);
  }
}

// XCD-chunked bijective remap (all grids here are multiples of 8).
__device__ __forceinline__ int xcd_remap(int id, int nwg) {
  return (id & 7) * (nwg >> 3) + (id >> 3);
}

// ======== R2-proven core: 128x128 tile, BK=64, double-buffered LDS,
// prefetch issued BEFORE compute, vmcnt(0)+__syncthreads at end of step.
__device__ __forceinline__ void core128(const bf16_t* __restrict__ Ag,
                                        const bf16_t* __restrict__ Bg,
                                        int Kloop, int lda, int ldb,
                                        bf16_t* As, bf16_t* Bs,
                                        floatx4 acc[4][4]) {
  const int tid = threadIdx.x;
  const int wid = tid >> 6, lane = tid & 63;
  const int wm = (wid >> 1) * 64, wn = (wid & 1) * 64;
  const int m16 = lane & 15, quad = lane >> 4;
  const int r7 = m16 & 7;
  constexpr int BUF = BM * 64;
  stage_swz<128, 64, 256>(Ag, lda, As, tid);
  stage_swz<128, 64, 256>(Bg, ldb, Bs, tid);
  asm volatile("s_waitcnt vmcnt(0)" ::: "memory");
  __syncthreads();
  int cur = 0;
  for (int k0 = 0; k0 < Kloop; k0 += 64) {
    if (k0 + 64 < Kloop) {
      stage_swz<128, 64, 256>(Ag + k0 + 64, lda, As + (cur ^ 1) * BUF, tid);
      stage_swz<128, 64, 256>(Bg + k0 + 64, ldb, Bs + (cur ^ 1) * BUF, tid);
    }
    const bf16_t* Ab = As + cur * BUF;
    const bf16_t* Bb = Bs + cur * BUF;
    #pragma unroll
    for (int ks = 0; ks < 2; ++ks) {
      const int gi = ks * 4 + quad;
      const int slot = gi ^ r7;
      bf16x8 af[4], bfr[4];
      #pragma unroll
      for (int mt = 0; mt < 4; ++mt)
        af[mt] = *(const bf16x8*)&Ab[((wm + mt * 16 + m16) * 8 + slot) * 8];
      #pragma unroll
      for (int nt = 0; nt < 4; ++nt)
        bfr[nt] = *(const bf16x8*)&Bb[((wn + nt * 16 + m16) * 8 + slot) * 8];
      #pragma unroll
      for (int mt = 0; mt < 4; ++mt)
        #pragma unroll
        for (int nt = 0; nt < 4; ++nt)
          acc[mt][nt] = __builtin_amdgcn_mfma_f32_16x16x32_bf16(af[mt], bfr[nt], acc[mt][nt], 0, 0, 0);
    }
    asm volatile("s_waitcnt vmcnt(0)" ::: "memory");
    __syncthreads();
    cur ^= 1;
  }
}

// ======== 8-phase core (m201 template port): 256x256, BK=64, 8 waves.
// Phase order per K-tile: (ks0,A0),(ks1,A0),(ks0,A1),(ks1,A1); B frags read in
// P0/P1 and HELD in regs for P2/P3 -> A0,B0,B1 of current buffer dead after P1,
// A1 dead after P3. Tile t+2 stages into those dead regions of the CURRENT
// buffer: (t,P2): A0+B0; (t,P3): B1; (t+1,P0): A1. Every load issued >=7 phases
// before its first read. One counted vmcnt(6) per tile boundary (waits exactly
// (t+1)A1 + everything older; (t+2)'s 6 loads stay in flight). Per phase:
// ds_read -> stage-issue -> s_barrier -> setprio(1) MFMA setprio(0) -> s_barrier.
__device__ __forceinline__ void core256_8ph(const bf16_t* __restrict__ Ag,
                                            const bf16_t* __restrict__ Bg,
                                            int Kloop, int lda, int ldb,
                                            bf16_t* As, bf16_t* Bs,
                                            floatx4 acc[8][4]) {
  const int tid = threadIdx.x;
  const int wid = tid >> 6, lane = tid & 63;
  const int wmh = ((wid >> 2) & 1) * 64;  // wave row offset inside each 128-half
  const int wn = (wid & 3) * 64;
  const int m16 = lane & 15, quad = lane >> 4;
  const int r7 = m16 & 7;
  constexpr int BUF = 256 * 64;
  constexpr int HALF = 128 * 64;
  const int NT = Kloop >> 6;
  // prologue: tile0 {A0,B0,B1,A1}, tile1 {A0,B0,B1}; wait tile0 (oldest 8 of 14)
  stage_swz<128, 64, 512>(Ag, lda, As, tid);
  stage_swz<128, 64, 512>(Bg, ldb, Bs, tid);
  stage_swz<128, 64, 512>(Bg + (size_t)128 * ldb, ldb, Bs + HALF, tid);
  stage_swz<128, 64, 512>(Ag + (size_t)128 * lda, lda, As + HALF, tid);
  stage_swz<128, 64, 512>(Ag + 64, lda, As + BUF, tid);
  stage_swz<128, 64, 512>(Bg + 64, ldb, Bs + BUF, tid);
  stage_swz<128, 64, 512>(Bg + 64 + (size_t)128 * ldb, ldb, Bs + BUF + HALF, tid);
  asm volatile("s_waitcnt vmcnt(6)" ::: "memory");
  asm volatile("s_barrier" ::: "memory");
  for (int t = 0; t < NT; ++t) {
    const int bt = (t & 1) * BUF;
    const int bn = bt ^ BUF;
    const bf16_t* Ab = As + bt;
    const bf16_t* Bb = Bs + bt;
    bf16x8 bfr0[4], bfr1[4], af[4];
    // ---- P0: (ks0, A0); stage (t+1)A1 -> other buffer ----
    #pragma unroll
    for (int nt = 0; nt < 4; ++nt)
      bfr0[nt] = *(const bf16x8*)&Bb[((wn + nt * 16 + m16) * 8 + (quad ^ r7)) * 8];
    #pragma unroll
    for (int j = 0; j < 4; ++j)
      af[j] = *(const bf16x8*)&Ab[((wmh + j * 16 + m16) * 8 + (quad ^ r7)) * 8];
    if (t + 1 < NT)
      stage_swz<128, 64, 512>(Ag + (size_t)(t + 1) * 64 + (size_t)128 * lda, lda,
                              As + bn + HALF, tid);
    asm volatile("s_barrier" ::: "memory");
    __builtin_amdgcn_s_setprio(1);
    #pragma unroll
    for (int j = 0; j < 4; ++j)
      #pragma unroll
      for (int nt = 0; nt < 4; ++nt)
        acc[j][nt] = __builtin_amdgcn_mfma_f32_16x16x32_bf16(af[j], bfr0[nt], acc[j][nt], 0, 0, 0);
    __builtin_amdgcn_s_setprio(0);
    asm volatile("s_barrier" ::: "memory");
    // ---- P1: (ks1, A0) ----
    #pragma unroll
    for (int nt = 0; nt < 4; ++nt)
      bfr1[nt] = *(const bf16x8*)&Bb[((wn + nt * 16 + m16) * 8 + ((4 + quad) ^ r7)) * 8];
    #pragma unroll
    for (int j = 0; j < 4; ++j)
      af[j] = *(const bf16x8*)&Ab[((wmh + j * 16 + m16) * 8 + ((4 + quad) ^ r7)) * 8];
    asm volatile("s_barrier" ::: "memory");
    __builtin_amdgcn_s_setprio(1);
    #pragma unroll
    for (int j = 0; j < 4; ++j)
      #pragma unroll
      for (int nt = 0; nt < 4; ++nt)
        acc[j][nt] = __builtin_amdgcn_mfma_f32_16x16x32_bf16(af[j], bfr1[nt], acc[j][nt], 0, 0, 0);
    __builtin_amdgcn_s_setprio(0);
    asm volatile("s_barrier" ::: "memory");
    // ---- P2: (ks0, A1); stage (t+2){A0,B0} into CURRENT buffer's dead regions ----
    #pragma unroll
    for (int j = 0; j < 4; ++j)
      af[j] = *(const bf16x8*)&Ab[((128 + wmh + j * 16 + m16) * 8 + (quad ^ r7)) * 8];
    if (t + 2 < NT) {
      stage_swz<128, 64, 512>(Ag + (size_t)(t + 2) * 64, lda, As + bt, tid);
      stage_swz<128, 64, 512>(Bg + (size_t)(t + 2) * 64, ldb, Bs + bt, tid);
    }
    asm volatile("s_barrier" ::: "memory");
    __builtin_amdgcn_s_setprio(1);
    #pragma unroll
    for (int j = 0; j < 4; ++j)
      #pragma unroll
      for (int nt = 0; nt < 4; ++nt)
        acc[4 + j][nt] = __builtin_amdgcn_mfma_f32_16x16x32_bf16(af[j], bfr0[nt], acc[4 + j][nt], 0, 0, 0);
    __builtin_amdgcn_s_setprio(0);
    asm volatile("s_barrier" ::: "memory");
    // ---- P3: (ks1, A1); stage (t+2)B1 ----
    #pragma unroll
    for (int j = 0; j < 4; ++j)
      af[j] = *(const bf16x8*)&Ab[((128 + wmh + j * 16 + m16) * 8 + ((4 + quad) ^ r7)) * 8];
    if (t + 2 < NT)
      stage_swz<128, 64, 512>(Bg + (size_t)(t + 2) * 64 + (size_t)128 * ldb, ldb,
                              Bs + bt + HALF, tid);
    asm volatile("s_barrier" ::: "memory");
    __builtin_amdgcn_s_setprio(1);
    #pragma unroll
    for (int j = 0; j < 4; ++j)
      #pragma unroll
      for (int nt = 0; nt < 4; ++nt)
        acc[4 + j][nt] = __builtin_amdgcn_mfma_f32_16x16x32_bf16(af[j], bfr1[nt], acc[4 + j][nt], 0, 0, 0);
    __builtin_amdgcn_s_setprio(0);
    // ---- boundary: counted wait, (t+2)'s loads stay in flight ----
    if (t + 1 < NT) {
      if (t + 2 < NT) asm volatile("s_waitcnt vmcnt(6)" ::: "memory");
      else            asm volatile("s_waitcnt vmcnt(0)" ::: "memory");
    }
    asm volatile("s_barrier" ::: "memory");
  }
}

// ---- 256x256 bf16 GEMM (W1: bias+relu); 8-phase core; XCD-chunked + GROUP_M=8 ----
template<int EPI>
__global__ __launch_bounds__(512)
void gemm256(const bf16_t* __restrict__ A, const bf16_t* __restrict__ B,
             bf16_t* __restrict__ C, const float* __restrict__ bias,
             int N, int K, int mblocks, int nblocks) {
  __shared__ bf16_t As[2 * 256 * 64];   // 64 KB
  __shared__ bf16_t Bs[2 * 256 * 64];   // 64 KB
  const int tid = threadIdx.x;
  const int wid = tid >> 6, lane = tid & 63;
  const int wmh = ((wid >> 2) & 1) * 64, wn = (wid & 3) * 64;
  const int m16 = lane & 15, quad = lane >> 4;
  const int id = xcd_remap(blockIdx.x, gridDim.x);
  const int per_group = 8 * nblocks;
  const int grp = id / per_group, rem = id % per_group;
  const int m0 = (grp * 8 + (rem & 7)) * 256;
  const int n0 = (rem >> 3) * 256;
  floatx4 acc[8][4];
  const floatx4 vzero = {0.f, 0.f, 0.f, 0.f};
  #pragma unroll
  for (int mt = 0; mt < 8; ++mt)
    #pragma unroll
    for (int nt = 0; nt < 4; ++nt) acc[mt][nt] = vzero;
  core256_8ph(A + (size_t)m0 * K, B + (size_t)n0 * K, K, K, K, As, Bs, acc);
  // 8-phase layout: acc[mh*4+j] covers rows mh*128 + wmh + j*16 (+quad*4+r)
  #pragma unroll
  for (int mh = 0; mh < 2; ++mh)
    #pragma unroll
    for (int j = 0; j < 4; ++j)
      #pragma unroll
      for (int nt = 0; nt < 4; ++nt) {
        const int gcol = n0 + wn + nt * 16 + m16;
        float bv = (EPI == EPI_BIAS_RELU) ? bias[gcol] : 0.f;
        #pragma unroll
        for (int r = 0; r < 4; ++r) {
          const int grow = m0 + mh * 128 + wmh + j * 16 + quad * 4 + r;
          float v = acc[mh * 4 + j][nt][r];
          if (EPI == EPI_BIAS_RELU) { v += bv; v = fmaxf(v, 0.f); }
          C[(size_t)grow * N + gcol] = (bf16_t)v;
        }
      }
}

// ---- fused QKV on 8-phase core; Q scaled 1/8; V transposed ----
__global__ __launch_bounds__(512)
void gemm_qkv(const bf16_t* __restrict__ X, const bf16_t* __restrict__ Wb,
              bf16_t* __restrict__ Qo, bf16_t* __restrict__ Ko, bf16_t* __restrict__ Vt) {
  __shared__ bf16_t As[2 * 256 * 64];
  __shared__ bf16_t Bs[2 * 256 * 64];
  const int tid = threadIdx.x;
  const int wid = tid >> 6, lane = tid & 63;
  const int wmh = ((wid >> 2) & 1) * 64, wn = (wid & 3) * 64;
  const int m16 = lane & 15, quad = lane >> 4;
  const int id = xcd_remap(blockIdx.x, gridDim.x);
  const int per_group = 8 * 12;            // GROUP_M=8 x (4 nblocks * 3 sel)
  const int grp = id / per_group, rem = id % per_group;
  const int m0 = (grp * 8 + (rem & 7)) * 256;
  const int nall = rem >> 3;               // 0..11
  const int n0 = (nall & 3) * 256;
  const int sel = nall >> 2;
  const bf16_t* B = Wb + (size_t)sel * 1024 * 1024;
  floatx4 acc[8][4];
  const floatx4 vzero = {0.f, 0.f, 0.f, 0.f};
  #pragma unroll
  for (int mt = 0; mt < 8; ++mt)
    #pragma unroll
    for (int nt = 0; nt < 4; ++nt) acc[mt][nt] = vzero;
  core256_8ph(X + (size_t)m0 * 1024, B + (size_t)n0 * 1024, 1024, 1024, 1024, As, Bs, acc);
  // 8-phase layout: acc[mh*4+j] covers rows mh*128 + wmh + j*16 (+quad*4+r)
  if (sel < 2) {
    bf16_t* C = sel ? Ko : Qo;
    const float sc = sel ? 1.f : 0.125f;
    #pragma unroll
    for (int mh = 0; mh < 2; ++mh)
      #pragma unroll
      for (int j = 0; j < 4; ++j)
        #pragma unroll
        for (int nt = 0; nt < 4; ++nt) {
          const int gcol = n0 + wn + nt * 16 + m16;
          #pragma unroll
          for (int r = 0; r < 4; ++r) {
            const int grow = m0 + mh * 128 + wmh + j * 16 + quad * 4 + r;
            C[(size_t)grow * 1024 + gcol] = (bf16_t)(acc[mh * 4 + j][nt][r] * sc);
          }
        }
  } else {
    #pragma unroll
    for (int mh = 0; mh < 2; ++mh)
      #pragma unroll
      for (int j = 0; j < 4; ++j) {
        const int grow0 = m0 + mh * 128 + wmh + j * 16 + quad * 4;
        const int b = grow0 >> 10, s = grow0 & 1023;
        #pragma unroll
        for (int nt = 0; nt < 4; ++nt) {
          const int gcol = n0 + wn + nt * 16 + m16;
          const int h = gcol >> 6, d = gcol & 63;
          #pragma unroll
          for (int r = 0; r < 4; ++r)
            Vt[(((size_t)b * 16 + h) * 64 + d) * 1024 + s + r] = (bf16_t)acc[mh * 4 + j][nt][r];
        }
      }
  }
}

// ---- 128x128 split-K=2; R2-proven core; XCD-chunked, GROUP_M=8 (Wo, W2) ----
__global__ __launch_bounds__(256)
void gemm128_sk(const bf16_t* __restrict__ A, const bf16_t* __restrict__ B,
                bf16_t* __restrict__ p0, bf16_t* __restrict__ p1,
                int N, int K, int ldb, int mblocks, int nblocks) {
  __shared__ bf16_t As[2 * BM * 64];
  __shared__ bf16_t Bs[2 * BM * 64];
  const int tid = threadIdx.x;
  const int wid = tid >> 6, lane = tid & 63;
  const int wm = (wid >> 1) * 64, wn = (wid & 1) * 64;
  const int m16 = lane & 15, quad = lane >> 4;
  const int id = xcd_remap(blockIdx.x, gridDim.x);
  const int per_kh = mblocks * nblocks;
  const int kh = id / per_kh;
  const int rem2 = id % per_kh;
  const int per_group = 8 * nblocks;
  const int grp = rem2 / per_group, rem = rem2 % per_group;
  const int m0 = (grp * 8 + (rem & 7)) * BM;
  const int n0 = (rem >> 3) * BM;
  const int Keff = K / 2;
  floatx4 acc[4][4];
  const floatx4 vzero = {0.f, 0.f, 0.f, 0.f};
  #pragma unroll
  for (int mt = 0; mt < 4; ++mt)
    #pragma unroll
    for (int nt = 0; nt < 4; ++nt) acc[mt][nt] = vzero;
  core128(A + (size_t)m0 * K + (size_t)kh * Keff,
          B + (size_t)n0 * ldb + (size_t)kh * Keff, Keff, K, ldb, As, Bs, acc);
  bf16_t* Cp = kh ? p1 : p0;
  #pragma unroll
  for (int mt = 0; mt < 4; ++mt)
    #pragma unroll
    for (int nt = 0; nt < 4; ++nt) {
      const int gcol = n0 + wn + nt * 16 + m16;
      #pragma unroll
      for (int r = 0; r < 4; ++r) {
        const int grow = m0 + wm + mt * 16 + quad * 4 + r;
        Cp[(size_t)grow * N + gcol] = (bf16_t)acc[mt][nt][r];
      }
    }
}

// ======== ql2 final GEMM: 128x64 tile, BK=64, R2-pipelined, 512 blocks (2/CU),
// 48 KB LDS; QL2 epilogue (bias + z-dot), fp32 out ========
__global__ __launch_bounds__(256)
void gemm64p(const bf16_t* __restrict__ A, const bf16_t* __restrict__ B,
             float* __restrict__ C, const float* __restrict__ bias,
             const bf16_t* __restrict__ z, const float* __restrict__ zw) {
  __shared__ bf16_t As[2 * 128 * 64];   // 32 KB
  __shared__ bf16_t Bs[2 * 64 * 64];    // 16 KB
  const int tid = threadIdx.x;
  const int wid = tid >> 6, lane = tid & 63;
  const int wm = (wid >> 1) * 64, wn = (wid & 1) * 32;
  const int m16 = lane & 15, quad = lane >> 4;
  const int r7 = m16 & 7;
  const int id = xcd_remap(blockIdx.x, gridDim.x);
  const int per_group = 8 * 16;   // GROUP_M=8 x 16 nblocks(64-wide)
  const int grp = id / per_group, rem = id % per_group;
  const int m0 = (grp * 8 + (rem & 7)) * 128;
  const int n0 = (rem >> 3) * 64;
  // B row n = output col n: ql2wb[n*1032 + 8 + k] (first 8 are z-weights)
  const bf16_t* Ag = A + (size_t)m0 * 1024;
  const bf16_t* Bg = B + (size_t)n0 * 1032 + 8;
  constexpr int ABUF = 128 * 64, BBUF = 64 * 64;
  floatx4 acc[4][2];
  const floatx4 vzero = {0.f, 0.f, 0.f, 0.f};
  #pragma unroll
  for (int mt = 0; mt < 4; ++mt)
    #pragma unroll
    for (int nt = 0; nt < 2; ++nt) acc[mt][nt] = vzero;
  stage_swz<128, 64, 256>(Ag, 1024, As, tid);
  stage_swz<64, 64, 256>(Bg, 1032, Bs, tid);
  asm volatile("s_waitcnt vmcnt(0)" ::: "memory");
  __syncthreads();
  int cur = 0;
  for (int k0 = 0; k0 < 1024; k0 += 64) {
    if (k0 + 64 < 1024) {
      stage_swz<128, 64, 256>(Ag + k0 + 64, 1024, As + (cur ^ 1) * ABUF, tid);
      stage_swz<64, 64, 256>(Bg + k0 + 64, 1032, Bs + (cur ^ 1) * BBUF, tid);
    }
    const bf16_t* Ab = As + cur * ABUF;
    const bf16_t* Bb = Bs + cur * BBUF;
    #pragma unroll
    for (int ks = 0; ks < 2; ++ks) {
      const int slot = (ks * 4 + quad) ^ r7;
      bf16x8 af[4], bfr[2];
      #pragma unroll
      for (int mt = 0; mt < 4; ++mt)
        af[mt] = *(const bf16x8*)&Ab[((wm + mt * 16 + m16) * 8 + slot) * 8];
      #pragma unroll
      for (int nt = 0; nt < 2; ++nt)
        bfr[nt] = *(const bf16x8*)&Bb[((wn + nt * 16 + m16) * 8 + slot) * 8];
      #pragma unroll
      for (int mt = 0; mt < 4; ++mt)
        #pragma unroll
        for (int nt = 0; nt < 2; ++nt)
          acc[mt][nt] = __builtin_amdgcn_mfma_f32_16x16x32_bf16(af[mt], bfr[nt], acc[mt][nt], 0, 0, 0);
    }
    asm volatile("s_waitcnt vmcnt(0)" ::: "memory");
    __syncthreads();
    cur ^= 1;
  }
  #pragma unroll
  for (int mt = 0; mt < 4; ++mt)
    #pragma unroll
    for (int nt = 0; nt < 2; ++nt) {
      const int gcol = n0 + wn + nt * 16 + m16;
      const float bv = bias[gcol];
      #pragma unroll
      for (int r = 0; r < 4; ++r) {
        const int grow = m0 + wm + mt * 16 + quad * 4 + r;
        float s = 0.f;
        #pragma unroll
        for (int u = 0; u < 8; ++u)
          s += (float)z[(size_t)grow * 8 + u] * zw[(size_t)gcol * 1032 + u];
        C[(size_t)grow * 1024 + gcol] = acc[mt][nt][r] + bv + s;
      }
    }
}

// ======== flash attention (R6-proven): DMA K/V, 2-deep, XCD-chunked heads ========
__global__ __launch_bounds__(256)
void attn_kernel(const bf16_t* __restrict__ Q, const bf16_t* __restrict__ Kb,
                 const bf16_t* __restrict__ Vt, bf16_t* __restrict__ O) {
  __shared__ bf16_t Qs[64 * 64];        // 8 KB
  __shared__ bf16_t Ks[2][128 * 64];    // 32 KB (double-buffered)
  __shared__ bf16_t Vs[64 * 128];       // 16 KB
  __shared__ bf16_t Ps[4][16 * 128];    // 16 KB
  const int tid = threadIdx.x;
  const int wid = tid >> 6, lane = tid & 63;
  const int m16 = lane & 15, quad = lane >> 4;
  const int id = blockIdx.x;
  const int bh = (id & 7) * 8 + ((id >> 3) & 7);
  const int qt = id >> 6;
  const int b = bh >> 4, h = bh & 15;
  const size_t qbase = ((size_t)(b * 1024 + qt * 64)) * 1024 + h * 64;
  const size_t kbase = ((size_t)(b * 1024)) * 1024 + h * 64;
  const size_t vbase = ((size_t)bh * 64) * 1024;
  #pragma unroll
  for (int i = 0; i < 2; ++i) {
    int ci = i * 256 + tid;
    int row = ci >> 3, cc = ci & 7;
    *(bf16x8*)&Qs[row * 64 + ((cc ^ (row & 7)) * 8)] =
        *(const bf16x8*)&Q[qbase + (size_t)row * 1024 + cc * 8];
  }
  stage_swz<128, 64, 256>(Kb + kbase, 1024, Ks[0], tid);
  asm volatile("s_waitcnt vmcnt(0)" ::: "memory");
  __syncthreads();
  const int qm = wid * 16 + m16;
  bf16x8 qf0 = *(const bf16x8*)&Qs[qm * 64 + ((quad ^ (qm & 7)) * 8)];
  bf16x8 qf1 = *(const bf16x8*)&Qs[qm * 64 + (((4 + quad) ^ (qm & 7)) * 8)];
  floatx4 oacc[4];
  float rs[4];
  const floatx4 vzero = {0.f, 0.f, 0.f, 0.f};
  #pragma unroll
  for (int dt = 0; dt < 4; ++dt) oacc[dt] = vzero;
  #pragma unroll
  for (int r = 0; r < 4; ++r) rs[r] = 0.f;
  for (int kt = 0; kt < 8; ++kt) {
    stage_swz<64, 128, 256>(Vt + vbase + kt * 128, 1024, Vs, tid);
    if (kt < 7)
      stage_swz<128, 64, 256>(Kb + kbase + (size_t)(kt + 1) * 128 * 1024, 1024, Ks[(kt + 1) & 1], tid);
    const bf16_t* Kc = Ks[kt & 1];
    floatx4 sa[8];
    #pragma unroll
    for (int nt = 0; nt < 8; ++nt) sa[nt] = vzero;
    #pragma unroll
    for (int nt = 0; nt < 8; ++nt) {
      const int n = nt * 16 + m16;
      bf16x8 kf0 = *(const bf16x8*)&Kc[n * 64 + ((quad ^ (n & 7)) * 8)];
      bf16x8 kf1 = *(const bf16x8*)&Kc[n * 64 + (((4 + quad) ^ (n & 7)) * 8)];
      sa[nt] = __builtin_amdgcn_mfma_f32_16x16x32_bf16(qf0, kf0, sa[nt], 0, 0, 0);
      sa[nt] = __builtin_amdgcn_mfma_f32_16x16x32_bf16(qf1, kf1, sa[nt], 0, 0, 0);
    }
    #pragma unroll
    for (int nt = 0; nt < 8; ++nt)
      #pragma unroll
      for (int r = 0; r < 4; ++r) {
        float pv = __expf(sa[nt][r]);
        rs[r] += pv;
        const int prow = quad * 4 + r;
        const int g = nt * 2 + (m16 >> 3);
        const int gs = (g & 8) | ((g & 7) ^ (prow & 7));
        Ps[wid][prow * 128 + gs * 8 + (m16 & 7)] = (bf16_t)pv;
      }
    asm volatile("s_waitcnt vmcnt(0)" ::: "memory");
    __syncthreads();
    bf16x8 pf[4];
    #pragma unroll
    for (int ksub = 0; ksub < 4; ++ksub) {
      const int g = ksub * 4 + quad;
      const int gs = (g & 8) | ((g & 7) ^ (m16 & 7));
      pf[ksub] = *(const bf16x8*)&Ps[wid][m16 * 128 + gs * 8];
    }
    #pragma unroll
    for (int dt = 0; dt < 4; ++dt) {
      const int n = dt * 16 + m16;
      #pragma unroll
      for (int ksub = 0; ksub < 4; ++ksub) {
        const int g = ksub * 4 + quad;
        const int gs = (g & 8) | ((g & 7) ^ (n & 7));
        bf16x8 vf = *(const bf16x8*)&Vs[n * 128 + gs * 8];
        oacc[dt] = __builtin_amdgcn_mfma_f32_16x16x32_bf16(pf[ksub], vf, oacc[dt], 0, 0, 0);
      }
    }
    __syncthreads();
  }
  #pragma unroll
  for (int r = 0; r < 4; ++r) {
    rs[r] += __shfl_xor(rs[r], 1);
    rs[r] += __shfl_xor(rs[r], 2);
    rs[r] += __shfl_xor(rs[r], 4);
    rs[r] += __shfl_xor(rs[r], 8);
  }
  const size_t obase = ((size_t)(b * 1024 + qt * 64 + wid * 16)) * 1024 + h * 64;
  #pragma unroll
  for (int dt = 0; dt < 4; ++dt)
    #pragma unroll
    for (int r = 0; r < 4; ++r)
      O[obase + (size_t)(quad * 4 + r) * 1024 + dt * 16 + m16] = (bf16_t)(oacc[dt][r] / rs[r]);
}

// ---------------- segmented fp32 -> bf16 conversion ----------------
struct Segs {
  const float* s[5];
  bf16_t* d[5];
  int n8[5];
};
__global__ __launch_bounds__(256)
void conv_multi(Segs sg) {
  const int zz = blockIdx.z;
  const float* in = sg.s[zz];
  bf16_t* out = sg.d[zz];
  const int n8 = sg.n8[zz];
  for (int i = blockIdx.x * 256 + threadIdx.x; i < n8; i += gridDim.x * 256) {
    const float* p = in + (size_t)i * 8;
    floatx4 a = *(const floatx4*)p;
    floatx4 b = *(const floatx4*)(p + 4);
    bf16x8 o;
    #pragma unroll
    for (int j = 0; j < 4; ++j) { o[j] = (bf16_t)a[j]; o[4 + j] = (bf16_t)b[j]; }
    *(bf16x8*)(out + (size_t)i * 8) = o;
  }
}

// ---------------- LN1 with split-K combine: in = p0 + p1 + resid ----------------
__global__ __launch_bounds__(256)
void ln_combine(const bf16_t* __restrict__ p0, const bf16_t* __restrict__ p1,
                const bf16_t* __restrict__ resid,
                const float* __restrict__ g, const float* __restrict__ b,
                bf16_t* __restrict__ out) {
  const int row = blockIdx.x * 4 + (threadIdx.x >> 6);
  const int lane = threadIdx.x & 63;
  const size_t base = (size_t)row * 1024 + lane * 16;
  bf16x8 a0 = *(const bf16x8*)&p0[base];
  bf16x8 a1 = *(const bf16x8*)&p0[base + 8];
  bf16x8 b0 = *(const bf16x8*)&p1[base];
  bf16x8 b1 = *(const bf16x8*)&p1[base + 8];
  bf16x8 c0 = *(const bf16x8*)&resid[base];
  bf16x8 c1 = *(const bf16x8*)&resid[base + 8];
  float f[16];
  #pragma unroll
  for (int j = 0; j < 8; ++j) {
    f[j]     = (float)a0[j] + (float)b0[j] + (float)c0[j];
    f[8 + j] = (float)a1[j] + (float)b1[j] + (float)c1[j];
  }
  float s = 0.f, ss = 0.f;
  #pragma unroll
  for (int j = 0; j < 16; ++j) { s += f[j]; ss += f[j] * f[j]; }
  #pragma unroll
  for (int off = 1; off < 64; off <<= 1) { s += __shfl_xor(s, off); ss += __shfl_xor(ss, off); }
  const float m = s * (1.f / 1024.f);
  const float inv_sd = rsqrtf(ss * (1.f / 1024.f) - m * m + 1e-5f);
  const float* gp = g + lane * 16;
  const float* bp = b + lane * 16;
  bf16x8 o0, o1;
  #pragma unroll
  for (int j = 0; j < 8; ++j) o0[j] = (bf16_t)((f[j] - m) * inv_sd * gp[j] + bp[j]);
  #pragma unroll
  for (int j = 0; j < 8; ++j) o1[j] = (bf16_t)((f[8 + j] - m) * inv_sd * gp[8 + j] + bp[8 + j]);
  *(bf16x8*)&out[base] = o0;
  *(bf16x8*)&out[base + 8] = o1;
}

// ---- fused: (W2 combine + b2 + resid) -> LN2 -> x2; quantum -> z; ql2w conv ----
__global__ __launch_bounds__(256)
void ln2_quantum(const bf16_t* __restrict__ p0, const bf16_t* __restrict__ p1,
                 const bf16_t* __restrict__ resid, const float* __restrict__ bias,
                 const float* __restrict__ g, const float* __restrict__ b,
                 bf16_t* __restrict__ x2,
                 const float* __restrict__ qw1, const float* __restrict__ qb1,
                 const float* __restrict__ qwt, bf16_t* __restrict__ zout,
                 const float* __restrict__ ql2w, bf16_t* __restrict__ ql2wb) {
  if (blockIdx.z == 1) {
    const int n8 = 1024 * 1032 / 8;
    for (int i = blockIdx.x * 256 + threadIdx.x; i < n8; i += gridDim.x * 256) {
      const float* p = ql2w + (size_t)i * 8;
      floatx4 a = *(const floatx4*)p;
      floatx4 bb = *(const floatx4*)(p + 4);
      bf16x8 o;
      #pragma unroll
      for (int j = 0; j < 4; ++j) { o[j] = (bf16_t)a[j]; o[4 + j] = (bf16_t)bb[j]; }
      *(bf16x8*)(ql2wb + (size_t)i * 8) = o;
    }
    return;
  }
  const int row = blockIdx.x * 4 + (threadIdx.x >> 6);
  const int lane = threadIdx.x & 63;
  const size_t base = (size_t)row * 1024 + lane * 16;
  bf16x8 a0 = *(const bf16x8*)&p0[base];
  bf16x8 a1 = *(const bf16x8*)&p0[base + 8];
  bf16x8 b0 = *(const bf16x8*)&p1[base];
  bf16x8 b1 = *(const bf16x8*)&p1[base + 8];
  bf16x8 c0 = *(const bf16x8*)&resid[base];
  bf16x8 c1 = *(const bf16x8*)&resid[base + 8];
  const float* bsp = bias + lane * 16;
  float f[16];
  #pragma unroll
  for (int j = 0; j < 8; ++j) {
    f[j]     = (float)a0[j] + (float)b0[j] + (float)c0[j] + bsp[j];
    f[8 + j] = (float)a1[j] + (float)b1[j] + (float)c1[j] + bsp[8 + j];
  }
  float s = 0.f, ss = 0.f;
  #pragma unroll
  for (int j = 0; j < 16; ++j) { s += f[j]; ss += f[j] * f[j]; }
  #pragma unroll
  for (int off = 1; off < 64; off <<= 1) { s += __shfl_xor(s, off); ss += __shfl_xor(ss, off); }
  const float m = s * (1.f / 1024.f);
  const float inv_sd = rsqrtf(ss * (1.f / 1024.f) - m * m + 1e-5f);
  const float* gp = g + lane * 16;
  const float* bp = b + lane * 16;
  bf16x8 o0, o1;
  #pragma unroll
  for (int j = 0; j < 8; ++j) o0[j] = (bf16_t)((f[j] - m) * inv_sd * gp[j] + bp[j]);
  #pragma unroll
  for (int j = 0; j < 8; ++j) o1[j] = (bf16_t)((f[8 + j] - m) * inv_sd * gp[8 + j] + bp[8 + j]);
  *(bf16x8*)&x2[base] = o0;
  *(bf16x8*)&x2[base + 8] = o1;
  float th[8];
  #pragma unroll
  for (int qq = 0; qq < 8; ++qq) {
    const float* wp = qw1 + (size_t)qq * 1024 + lane * 16;
    float sdot = 0.f;
    #pragma unroll
    for (int j = 0; j < 8; ++j)
      sdot += (float)o0[j] * wp[j] + (float)o1[j] * wp[8 + j];
    #pragma unroll
    for (int off = 1; off < 64; off <<= 1) sdot += __shfl_xor(sdot, off);
    th[qq] = sdot + qb1[qq] + qwt[qq];
  }
  if (lane == 0) {
    float c[8];
    #pragma unroll
    for (int qq = 0; qq < 8; ++qq) c[qq] = cosf(th[qq]);
    float z0 = 1.f;
    #pragma unroll
    for (int u = 1; u < 8; ++u) z0 *= c[u];
    zout[(size_t)row * 8 + 0] = (bf16_t)z0;
    float pp = c[0];
    #pragma unroll
    for (int w = 1; w < 8; ++w) { pp *= c[w]; zout[(size_t)row * 8 + w] = (bf16_t)pp; }
  }
}

extern "C" void kernel_launch(void* const* d_in, const int* in_sizes, int n_in,
                              void* d_out, int out_size, void* d_ws, size_t ws_size,
                              hipStream_t stream) {
  const float* x    = (const float*)d_in[0];
  const float* Wq   = (const float*)d_in[1];
  const float* Wk   = (const float*)d_in[2];
  const float* Wv   = (const float*)d_in[3];
  const float* Wo   = (const float*)d_in[4];
  const float* ln1g = (const float*)d_in[5];
  const float* ln1b = (const float*)d_in[6];
  const float* W1   = (const float*)d_in[7];
  const float* b1   = (const float*)d_in[8];
  const float* W2   = (const float*)d_in[9];
  const float* b2   = (const float*)d_in[10];
  const float* ln2g = (const float*)d_in[11];
  const float* ln2b = (const float*)d_in[12];
  const float* qw1  = (const float*)d_in[13];
  const float* qb1  = (const float*)d_in[14];
  const float* qwt  = (const float*)d_in[15];
  const float* ql2w = (const float*)d_in[16];
  const float* ql2b = (const float*)d_in[17];
  bf16_t* ws = (bf16_t*)d_ws;

  const size_t T = (size_t)4096 * 1024;
  const size_t M1 = (size_t)1024 * 1024;
  bf16_t* outlo = (bf16_t*)d_out;
  bf16_t* outhi = outlo + T;

  bf16_t* xb    = ws;            // x bf16; resid for LN1; then W2 partial p0
  bf16_t* kb    = ws + T;        // K; Wo partial p1; then w2b; then z
  bf16_t* vt    = ws + 2 * T;    // V^T; then w1b; then W2 partial p1 / x2
  bf16_t* ff    = ws + 3 * T;    // wqkvb+wob; then FFN hidden; then ql2wb
  bf16_t* wqkvb = ff;
  bf16_t* wob   = ff + 3 * M1;
  bf16_t* w1b   = vt;
  bf16_t* w2b   = kb;
  bf16_t* ql2wb = ff;
  bf16_t* q     = outlo;
  bf16_t* o     = outhi;
  bf16_t* x1    = outhi;         // LN1 out (o dead)
  bf16_t* x2    = vt;            // LN2 out (in-place over W2 p1)
  bf16_t* z     = kb;

  {
    Segs sg;
    sg.s[0] = x;  sg.d[0] = xb;            sg.n8[0] = (int)(T / 8);
    sg.s[1] = Wq; sg.d[1] = wqkvb;         sg.n8[1] = (int)(M1 / 8);
    sg.s[2] = Wk; sg.d[2] = wqkvb + M1;    sg.n8[2] = (int)(M1 / 8);
    sg.s[3] = Wv; sg.d[3] = wqkvb + 2*M1;  sg.n8[3] = (int)(M1 / 8);
    sg.s[4] = Wo; sg.d[4] = wob;           sg.n8[4] = (int)(M1 / 8);
    conv_multi<<<dim3(512, 1, 5), 256, 0, stream>>>(sg);
  }
  gemm_qkv<<<192, 512, 0, stream>>>(xb, wqkvb, q, kb, vt);
  attn_kernel<<<1024, 256, 0, stream>>>(q, kb, vt, o);
  // Wo split-K=2 on 128x128 tile: partials outlo (q dead) + kb (K dead).
  gemm128_sk<<<512, 256, 0, stream>>>(o, wob, outlo, kb, 1024, 1024, 1024, 32, 8);
  ln_combine<<<1024, 256, 0, stream>>>(outlo, kb, xb, ln1g, ln1b, x1);
  {
    Segs sg;
    sg.s[0] = W1; sg.d[0] = w1b; sg.n8[0] = (int)(T / 8);
    sg.s[1] = W2; sg.d[1] = w2b; sg.n8[1] = (int)(T / 8);
    sg.s[2] = nullptr; sg.d[2] = nullptr; sg.n8[2] = 0;
    sg.s[3] = nullptr; sg.d[3] = nullptr; sg.n8[3] = 0;
    sg.s[4] = nullptr; sg.d[4] = nullptr; sg.n8[4] = 0;
    conv_multi<<<dim3(1024, 1, 2), 256, 0, stream>>>(sg);
  }
  gemm256<EPI_BIAS_RELU><<<256, 512, 0, stream>>>(x1, w1b, ff, b1, 4096, 1024, 16, 16);
  // W2 split-K=2 on 128x128 tile: partials xb (x dead) + vt (w1b dead).
  gemm128_sk<<<512, 256, 0, stream>>>(ff, w2b, xb, vt, 1024, 4096, 4096, 32, 8);
  ln2_quantum<<<dim3(1024, 1, 2), 256, 0, stream>>>(
      xb, vt, x1, b2, ln2g, ln2b, x2, qw1, qb1, qwt, z, ql2w, ql2wb);
  gemm64p<<<512, 256, 0, stream>>>(x2, ql2wb, (float*)d_out, ql2b, z, ql2w);
}

// Round 11
// 365.877 us; speedup vs baseline: 1.0223x; 1.0088x over previous
//
#include <hip/hip_runtime.h>
#include <hip/hip_bf16.h>

typedef __bf16 bf16_t;
typedef __attribute__((ext_vector_type(8))) __bf16 bf16x8;
typedef __attribute__((ext_vector_type(4))) float floatx4;

#define BM 128

enum { EPI_NONE = 0, EPI_RESID, EPI_BIAS_RELU, EPI_BIAS_RESID, EPI_QL2, EPI_PART };

__device__ __forceinline__ void gld_lds16(const bf16_t* g, bf16_t* l) {
  __builtin_amdgcn_global_load_lds(
      (__attribute__((address_space(1))) void*)(g),
      (__attribute__((address_space(3))) void*)(l), 16, 0, 0);
}

// Swizzled DMA staging: LDS slot ci=(row,cc) receives GLOBAL granule cc^(row&7).
template<int ROWS, int COLS, int NTHR>
__device__ __forceinline__ void stage_swz(const bf16_t* g, int ld, bf16_t* lds, int tid) {
  constexpr int G = COLS / 8;
  #pragma unroll
  for (int i = 0; i < ROWS * G / NTHR; ++i) {
    int ci = i * NTHR + tid;
    int row = ci / G, cc = ci % G;
    int gg = (G == 8) ? (cc ^ (row & 7)) : ((cc & 8) | ((cc & 7) ^ (row & 7)));
    gld_lds16(g + (size_t)row * ld + gg * 8, lds + ci * 8);
  }
}

// XCD-chunked bijective remap (nwg must be a multiple of 8).
__device__ __forceinline__ int xcd_remap(int id, int nwg) {
  return (id & 7) * (nwg >> 3) + (id >> 3);
}

// fp32 -> bf16 conversion helper (grid-stride over n8 bf16x8 items)
__device__ __forceinline__ void conv_f32_bf16(const float* in, bf16_t* out,
                                              int n8, int idx, int stride) {
  for (int i = idx; i < n8; i += stride) {
    const float* p = in + (size_t)i * 8;
    floatx4 a = *(const floatx4*)p;
    floatx4 b = *(const floatx4*)(p + 4);
    bf16x8 o;
    #pragma unroll
    for (int j = 0; j < 4; ++j) { o[j] = (bf16_t)a[j]; o[4 + j] = (bf16_t)b[j]; }
    *(bf16x8*)(out + (size_t)i * 8) = o;
  }
}

// ======== R2-proven core: 128x128 tile, BK=64, double-buffered LDS,
// prefetch issued BEFORE compute, vmcnt(0)+__syncthreads at end of step.
__device__ __forceinline__ void core128(const bf16_t* __restrict__ Ag,
                                        const bf16_t* __restrict__ Bg,
                                        int Kloop, int lda, int ldb,
                                        bf16_t* As, bf16_t* Bs,
                                        floatx4 acc[4][4]) {
  const int tid = threadIdx.x;
  const int wid = tid >> 6, lane = tid & 63;
  const int wm = (wid >> 1) * 64, wn = (wid & 1) * 64;
  const int m16 = lane & 15, quad = lane >> 4;
  const int r7 = m16 & 7;
  constexpr int BUF = BM * 64;
  stage_swz<128, 64, 256>(Ag, lda, As, tid);
  stage_swz<128, 64, 256>(Bg, ldb, Bs, tid);
  asm volatile("s_waitcnt vmcnt(0)" ::: "memory");
  __syncthreads();
  int cur = 0;
  for (int k0 = 0; k0 < Kloop; k0 += 64) {
    if (k0 + 64 < Kloop) {
      stage_swz<128, 64, 256>(Ag + k0 + 64, lda, As + (cur ^ 1) * BUF, tid);
      stage_swz<128, 64, 256>(Bg + k0 + 64, ldb, Bs + (cur ^ 1) * BUF, tid);
    }
    const bf16_t* Ab = As + cur * BUF;
    const bf16_t* Bb = Bs + cur * BUF;
    #pragma unroll
    for (int ks = 0; ks < 2; ++ks) {
      const int gi = ks * 4 + quad;
      const int slot = gi ^ r7;
      bf16x8 af[4], bfr[4];
      #pragma unroll
      for (int mt = 0; mt < 4; ++mt)
        af[mt] = *(const bf16x8*)&Ab[((wm + mt * 16 + m16) * 8 + slot) * 8];
      #pragma unroll
      for (int nt = 0; nt < 4; ++nt)
        bfr[nt] = *(const bf16x8*)&Bb[((wn + nt * 16 + m16) * 8 + slot) * 8];
      #pragma unroll
      for (int mt = 0; mt < 4; ++mt)
        #pragma unroll
        for (int nt = 0; nt < 4; ++nt)
          acc[mt][nt] = __builtin_amdgcn_mfma_f32_16x16x32_bf16(af[mt], bfr[nt], acc[mt][nt], 0, 0, 0);
    }
    asm volatile("s_waitcnt vmcnt(0)" ::: "memory");
    __syncthreads();
    cur ^= 1;
  }
}

// ======== 8-phase core (m201 template port): 256x256, BK=64, 8 waves.
// Phase order per K-tile: (ks0,A0),(ks1,A0),(ks0,A1),(ks1,A1); B frags read in
// P0/P1 and HELD in regs for P2/P3 -> A0,B0,B1 of current buffer dead after P1,
// A1 dead after P3. Tile t+2 stages into those dead regions of the CURRENT
// buffer: (t,P2): A0+B0; (t,P3): B1; (t+1,P0): A1. Every load issued >=7 phases
// before its first read. One counted vmcnt(6) per tile boundary.
__device__ __forceinline__ void core256_8ph(const bf16_t* __restrict__ Ag,
                                            const bf16_t* __restrict__ Bg,
                                            int Kloop, int lda, int ldb,
                                            bf16_t* As, bf16_t* Bs,
                                            floatx4 acc[8][4]) {
  const int tid = threadIdx.x;
  const int wid = tid >> 6, lane = tid & 63;
  const int wmh = ((wid >> 2) & 1) * 64;  // wave row offset inside each 128-half
  const int wn = (wid & 3) * 64;
  const int m16 = lane & 15, quad = lane >> 4;
  const int r7 = m16 & 7;
  constexpr int BUF = 256 * 64;
  constexpr int HALF = 128 * 64;
  const int NT = Kloop >> 6;
  // prologue: tile0 {A0,B0,B1,A1}, tile1 {A0,B0,B1}; wait tile0 (oldest 8 of 14)
  stage_swz<128, 64, 512>(Ag, lda, As, tid);
  stage_swz<128, 64, 512>(Bg, ldb, Bs, tid);
  stage_swz<128, 64, 512>(Bg + (size_t)128 * ldb, ldb, Bs + HALF, tid);
  stage_swz<128, 64, 512>(Ag + (size_t)128 * lda, lda, As + HALF, tid);
  stage_swz<128, 64, 512>(Ag + 64, lda, As + BUF, tid);
  stage_swz<128, 64, 512>(Bg + 64, ldb, Bs + BUF, tid);
  stage_swz<128, 64, 512>(Bg + 64 + (size_t)128 * ldb, ldb, Bs + BUF + HALF, tid);
  asm volatile("s_waitcnt vmcnt(6)" ::: "memory");
  asm volatile("s_barrier" ::: "memory");
  for (int t = 0; t < NT; ++t) {
    const int bt = (t & 1) * BUF;
    const int bn = bt ^ BUF;
    const bf16_t* Ab = As + bt;
    const bf16_t* Bb = Bs + bt;
    bf16x8 bfr0[4], bfr1[4], af[4];
    // ---- P0: (ks0, A0); stage (t+1)A1 -> other buffer ----
    #pragma unroll
    for (int nt = 0; nt < 4; ++nt)
      bfr0[nt] = *(const bf16x8*)&Bb[((wn + nt * 16 + m16) * 8 + (quad ^ r7)) * 8];
    #pragma unroll
    for (int j = 0; j < 4; ++j)
      af[j] = *(const bf16x8*)&Ab[((wmh + j * 16 + m16) * 8 + (quad ^ r7)) * 8];
    if (t + 1 < NT)
      stage_swz<128, 64, 512>(Ag + (size_t)(t + 1) * 64 + (size_t)128 * lda, lda,
                              As + bn + HALF, tid);
    asm volatile("s_barrier" ::: "memory");
    __builtin_amdgcn_s_setprio(1);
    #pragma unroll
    for (int j = 0; j < 4; ++j)
      #pragma unroll
      for (int nt = 0; nt < 4; ++nt)
        acc[j][nt] = __builtin_amdgcn_mfma_f32_16x16x32_bf16(af[j], bfr0[nt], acc[j][nt], 0, 0, 0);
    __builtin_amdgcn_s_setprio(0);
    asm volatile("s_barrier" ::: "memory");
    // ---- P1: (ks1, A0) ----
    #pragma unroll
    for (int nt = 0; nt < 4; ++nt)
      bfr1[nt] = *(const bf16x8*)&Bb[((wn + nt * 16 + m16) * 8 + ((4 + quad) ^ r7)) * 8];
    #pragma unroll
    for (int j = 0; j < 4; ++j)
      af[j] = *(const bf16x8*)&Ab[((wmh + j * 16 + m16) * 8 + ((4 + quad) ^ r7)) * 8];
    asm volatile("s_barrier" ::: "memory");
    __builtin_amdgcn_s_setprio(1);
    #pragma unroll
    for (int j = 0; j < 4; ++j)
      #pragma unroll
      for (int nt = 0; nt < 4; ++nt)
        acc[j][nt] = __builtin_amdgcn_mfma_f32_16x16x32_bf16(af[j], bfr1[nt], acc[j][nt], 0, 0, 0);
    __builtin_amdgcn_s_setprio(0);
    asm volatile("s_barrier" ::: "memory");
    // ---- P2: (ks0, A1); stage (t+2){A0,B0} into CURRENT buffer's dead regions ----
    #pragma unroll
    for (int j = 0; j < 4; ++j)
      af[j] = *(const bf16x8*)&Ab[((128 + wmh + j * 16 + m16) * 8 + (quad ^ r7)) * 8];
    if (t + 2 < NT) {
      stage_swz<128, 64, 512>(Ag + (size_t)(t + 2) * 64, lda, As + bt, tid);
      stage_swz<128, 64, 512>(Bg + (size_t)(t + 2) * 64, ldb, Bs + bt, tid);
    }
    asm volatile("s_barrier" ::: "memory");
    __builtin_amdgcn_s_setprio(1);
    #pragma unroll
    for (int j = 0; j < 4; ++j)
      #pragma unroll
      for (int nt = 0; nt < 4; ++nt)
        acc[4 + j][nt] = __builtin_amdgcn_mfma_f32_16x16x32_bf16(af[j], bfr0[nt], acc[4 + j][nt], 0, 0, 0);
    __builtin_amdgcn_s_setprio(0);
    asm volatile("s_barrier" ::: "memory");
    // ---- P3: (ks1, A1); stage (t+2)B1 ----
    #pragma unroll
    for (int j = 0; j < 4; ++j)
      af[j] = *(const bf16x8*)&Ab[((128 + wmh + j * 16 + m16) * 8 + ((4 + quad) ^ r7)) * 8];
    if (t + 2 < NT)
      stage_swz<128, 64, 512>(Bg + (size_t)(t + 2) * 64 + (size_t)128 * ldb, ldb,
                              Bs + bt + HALF, tid);
    asm volatile("s_barrier" ::: "memory");
    __builtin_amdgcn_s_setprio(1);
    #pragma unroll
    for (int j = 0; j < 4; ++j)
      #pragma unroll
      for (int nt = 0; nt < 4; ++nt)
        acc[4 + j][nt] = __builtin_amdgcn_mfma_f32_16x16x32_bf16(af[j], bfr1[nt], acc[4 + j][nt], 0, 0, 0);
    __builtin_amdgcn_s_setprio(0);
    // ---- boundary: counted wait, (t+2)'s loads stay in flight ----
    if (t + 1 < NT) {
      if (t + 2 < NT) asm volatile("s_waitcnt vmcnt(6)" ::: "memory");
      else            asm volatile("s_waitcnt vmcnt(0)" ::: "memory");
    }
    asm volatile("s_barrier" ::: "memory");
  }
}

// ---- 256x256 bf16 GEMM (W1: bias+relu) + fused W2 fp32->bf16 conversion.
// Blocks [0,256): GEMM (XCD-chunked + GROUP_M=8). Blocks [256,512): conv W2
// into w2dst (kb region; p1 consumed by previous launch, w2b needed by next).
// Conv traffic hides under the GEMM tail as gemm blocks retire.
template<int EPI>
__global__ __launch_bounds__(512)
void gemm256(const bf16_t* __restrict__ A, const bf16_t* __restrict__ B,
             bf16_t* __restrict__ C, const float* __restrict__ bias,
             int N, int K, int mblocks, int nblocks,
             const float* __restrict__ w2src, bf16_t* __restrict__ w2dst) {
  __shared__ bf16_t As[2 * 256 * 64];   // 64 KB
  __shared__ bf16_t Bs[2 * 256 * 64];   // 64 KB
  const int tid = threadIdx.x;
  if (blockIdx.x >= 256) {
    const int n8 = (int)((size_t)4096 * 1024 / 8);
    conv_f32_bf16(w2src, w2dst, n8, (blockIdx.x - 256) * 512 + tid, 256 * 512);
    return;
  }
  const int wid = tid >> 6, lane = tid & 63;
  const int wmh = ((wid >> 2) & 1) * 64, wn = (wid & 3) * 64;
  const int m16 = lane & 15, quad = lane >> 4;
  const int id = xcd_remap(blockIdx.x, 256);
  const int per_group = 8 * nblocks;
  const int grp = id / per_group, rem = id % per_group;
  const int m0 = (grp * 8 + (rem & 7)) * 256;
  const int n0 = (rem >> 3) * 256;
  floatx4 acc[8][4];
  const floatx4 vzero = {0.f, 0.f, 0.f, 0.f};
  #pragma unroll
  for (int mt = 0; mt < 8; ++mt)
    #pragma unroll
    for (int nt = 0; nt < 4; ++nt) acc[mt][nt] = vzero;
  core256_8ph(A + (size_t)m0 * K, B + (size_t)n0 * K, K, K, K, As, Bs, acc);
  // 8-phase layout: acc[mh*4+j] covers rows mh*128 + wmh + j*16 (+quad*4+r)
  #pragma unroll
  for (int mh = 0; mh < 2; ++mh)
    #pragma unroll
    for (int j = 0; j < 4; ++j)
      #pragma unroll
      for (int nt = 0; nt < 4; ++nt) {
        const int gcol = n0 + wn + nt * 16 + m16;
        float bv = (EPI == EPI_BIAS_RELU) ? bias[gcol] : 0.f;
        #pragma unroll
        for (int r = 0; r < 4; ++r) {
          const int grow = m0 + mh * 128 + wmh + j * 16 + quad * 4 + r;
          float v = acc[mh * 4 + j][nt][r];
          if (EPI == EPI_BIAS_RELU) { v += bv; v = fmaxf(v, 0.f); }
          C[(size_t)grow * N + gcol] = (bf16_t)v;
        }
      }
}

// ---- fused QKV on 8-phase core; Q scaled 1/8; V transposed ----
__global__ __launch_bounds__(512)
void gemm_qkv(const bf16_t* __restrict__ X, const bf16_t* __restrict__ Wb,
              bf16_t* __restrict__ Qo, bf16_t* __restrict__ Ko, bf16_t* __restrict__ Vt) {
  __shared__ bf16_t As[2 * 256 * 64];
  __shared__ bf16_t Bs[2 * 256 * 64];
  const int tid = threadIdx.x;
  const int wid = tid >> 6, lane = tid & 63;
  const int wmh = ((wid >> 2) & 1) * 64, wn = (wid & 3) * 64;
  const int m16 = lane & 15, quad = lane >> 4;
  const int id = xcd_remap(blockIdx.x, gridDim.x);
  const int per_group = 8 * 12;            // GROUP_M=8 x (4 nblocks * 3 sel)
  const int grp = id / per_group, rem = id % per_group;
  const int m0 = (grp * 8 + (rem & 7)) * 256;
  const int nall = rem >> 3;               // 0..11
  const int n0 = (nall & 3) * 256;
  const int sel = nall >> 2;
  const bf16_t* B = Wb + (size_t)sel * 1024 * 1024;
  floatx4 acc[8][4];
  const floatx4 vzero = {0.f, 0.f, 0.f, 0.f};
  #pragma unroll
  for (int mt = 0; mt < 8; ++mt)
    #pragma unroll
    for (int nt = 0; nt < 4; ++nt) acc[mt][nt] = vzero;
  core256_8ph(X + (size_t)m0 * 1024, B + (size_t)n0 * 1024, 1024, 1024, 1024, As, Bs, acc);
  // 8-phase layout: acc[mh*4+j] covers rows mh*128 + wmh + j*16 (+quad*4+r)
  if (sel < 2) {
    bf16_t* C = sel ? Ko : Qo;
    const float sc = sel ? 1.f : 0.125f;
    #pragma unroll
    for (int mh = 0; mh < 2; ++mh)
      #pragma unroll
      for (int j = 0; j < 4; ++j)
        #pragma unroll
        for (int nt = 0; nt < 4; ++nt) {
          const int gcol = n0 + wn + nt * 16 + m16;
          #pragma unroll
          for (int r = 0; r < 4; ++r) {
            const int grow = m0 + mh * 128 + wmh + j * 16 + quad * 4 + r;
            C[(size_t)grow * 1024 + gcol] = (bf16_t)(acc[mh * 4 + j][nt][r] * sc);
          }
        }
  } else {
    #pragma unroll
    for (int mh = 0; mh < 2; ++mh)
      #pragma unroll
      for (int j = 0; j < 4; ++j) {
        const int grow0 = m0 + mh * 128 + wmh + j * 16 + quad * 4;
        const int b = grow0 >> 10, s = grow0 & 1023;
        #pragma unroll
        for (int nt = 0; nt < 4; ++nt) {
          const int gcol = n0 + wn + nt * 16 + m16;
          const int h = gcol >> 6, d = gcol & 63;
          #pragma unroll
          for (int r = 0; r < 4; ++r)
            Vt[(((size_t)b * 16 + h) * 64 + d) * 1024 + s + r] = (bf16_t)acc[mh * 4 + j][nt][r];
        }
      }
  }
}

// ---- 128x128 split-K=2; R2-proven core; XCD-chunked, GROUP_M=8 (Wo, W2) ----
__global__ __launch_bounds__(256)
void gemm128_sk(const bf16_t* __restrict__ A, const bf16_t* __restrict__ B,
                bf16_t* __restrict__ p0, bf16_t* __restrict__ p1,
                int N, int K, int ldb, int mblocks, int nblocks) {
  __shared__ bf16_t As[2 * BM * 64];
  __shared__ bf16_t Bs[2 * BM * 64];
  const int tid = threadIdx.x;
  const int wid = tid >> 6, lane = tid & 63;
  const int wm = (wid >> 1) * 64, wn = (wid & 1) * 64;
  const int m16 = lane & 15, quad = lane >> 4;
  const int id = xcd_remap(blockIdx.x, gridDim.x);
  const int per_kh = mblocks * nblocks;
  const int kh = id / per_kh;
  const int rem2 = id % per_kh;
  const int per_group = 8 * nblocks;
  const int grp = rem2 / per_group, rem = rem2 % per_group;
  const int m0 = (grp * 8 + (rem & 7)) * BM;
  const int n0 = (rem >> 3) * BM;
  const int Keff = K / 2;
  floatx4 acc[4][4];
  const floatx4 vzero = {0.f, 0.f, 0.f, 0.f};
  #pragma unroll
  for (int mt = 0; mt < 4; ++mt)
    #pragma unroll
    for (int nt = 0; nt < 4; ++nt) acc[mt][nt] = vzero;
  core128(A + (size_t)m0 * K + (size_t)kh * Keff,
          B + (size_t)n0 * ldb + (size_t)kh * Keff, Keff, K, ldb, As, Bs, acc);
  bf16_t* Cp = kh ? p1 : p0;
  #pragma unroll
  for (int mt = 0; mt < 4; ++mt)
    #pragma unroll
    for (int nt = 0; nt < 4; ++nt) {
      const int gcol = n0 + wn + nt * 16 + m16;
      #pragma unroll
      for (int r = 0; r < 4; ++r) {
        const int grow = m0 + wm + mt * 16 + quad * 4 + r;
        Cp[(size_t)grow * N + gcol] = (bf16_t)acc[mt][nt][r];
      }
    }
}

// ======== ql2 final GEMM: 128x64 tile, BK=64, R2-pipelined, 512 blocks (2/CU),
// 48 KB LDS; QL2 epilogue (bias + z-dot), fp32 out ========
__global__ __launch_bounds__(256)
void gemm64p(const bf16_t* __restrict__ A, const bf16_t* __restrict__ B,
             float* __restrict__ C, const float* __restrict__ bias,
             const bf16_t* __restrict__ z, const float* __restrict__ zw) {
  __shared__ bf16_t As[2 * 128 * 64];   // 32 KB
  __shared__ bf16_t Bs[2 * 64 * 64];    // 16 KB
  const int tid = threadIdx.x;
  const int wid = tid >> 6, lane = tid & 63;
  const int wm = (wid >> 1) * 64, wn = (wid & 1) * 32;
  const int m16 = lane & 15, quad = lane >> 4;
  const int r7 = m16 & 7;
  const int id = xcd_remap(blockIdx.x, gridDim.x);
  const int per_group = 8 * 16;   // GROUP_M=8 x 16 nblocks(64-wide)
  const int grp = id / per_group, rem = id % per_group;
  const int m0 = (grp * 8 + (rem & 7)) * 128;
  const int n0 = (rem >> 3) * 64;
  // B row n = output col n: ql2wb[n*1032 + 8 + k] (first 8 are z-weights)
  const bf16_t* Ag = A + (size_t)m0 * 1024;
  const bf16_t* Bg = B + (size_t)n0 * 1032 + 8;
  constexpr int ABUF = 128 * 64, BBUF = 64 * 64;
  floatx4 acc[4][2];
  const floatx4 vzero = {0.f, 0.f, 0.f, 0.f};
  #pragma unroll
  for (int mt = 0; mt < 4; ++mt)
    #pragma unroll
    for (int nt = 0; nt < 2; ++nt) acc[mt][nt] = vzero;
  stage_swz<128, 64, 256>(Ag, 1024, As, tid);
  stage_swz<64, 64, 256>(Bg, 1032, Bs, tid);
  asm volatile("s_waitcnt vmcnt(0)" ::: "memory");
  __syncthreads();
  int cur = 0;
  for (int k0 = 0; k0 < 1024; k0 += 64) {
    if (k0 + 64 < 1024) {
      stage_swz<128, 64, 256>(Ag + k0 + 64, 1024, As + (cur ^ 1) * ABUF, tid);
      stage_swz<64, 64, 256>(Bg + k0 + 64, 1032, Bs + (cur ^ 1) * BBUF, tid);
    }
    const bf16_t* Ab = As + cur * ABUF;
    const bf16_t* Bb = Bs + cur * BBUF;
    #pragma unroll
    for (int ks = 0; ks < 2; ++ks) {
      const int slot = (ks * 4 + quad) ^ r7;
      bf16x8 af[4], bfr[2];
      #pragma unroll
      for (int mt = 0; mt < 4; ++mt)
        af[mt] = *(const bf16x8*)&Ab[((wm + mt * 16 + m16) * 8 + slot) * 8];
      #pragma unroll
      for (int nt = 0; nt < 2; ++nt)
        bfr[nt] = *(const bf16x8*)&Bb[((wn + nt * 16 + m16) * 8 + slot) * 8];
      #pragma unroll
      for (int mt = 0; mt < 4; ++mt)
        #pragma unroll
        for (int nt = 0; nt < 2; ++nt)
          acc[mt][nt] = __builtin_amdgcn_mfma_f32_16x16x32_bf16(af[mt], bfr[nt], acc[mt][nt], 0, 0, 0);
    }
    asm volatile("s_waitcnt vmcnt(0)" ::: "memory");
    __syncthreads();
    cur ^= 1;
  }
  #pragma unroll
  for (int mt = 0; mt < 4; ++mt)
    #pragma unroll
    for (int nt = 0; nt < 2; ++nt) {
      const int gcol = n0 + wn + nt * 16 + m16;
      const float bv = bias[gcol];
      #pragma unroll
      for (int r = 0; r < 4; ++r) {
        const int grow = m0 + wm + mt * 16 + quad * 4 + r;
        float s = 0.f;
        #pragma unroll
        for (int u = 0; u < 8; ++u)
          s += (float)z[(size_t)grow * 8 + u] * zw[(size_t)gcol * 1032 + u];
        C[(size_t)grow * 1024 + gcol] = acc[mt][nt][r] + bv + s;
      }
    }
}

// ======== flash attention (R6-proven): DMA K/V, 2-deep, XCD-chunked heads ========
__global__ __launch_bounds__(256)
void attn_kernel(const bf16_t* __restrict__ Q, const bf16_t* __restrict__ Kb,
                 const bf16_t* __restrict__ Vt, bf16_t* __restrict__ O) {
  __shared__ bf16_t Qs[64 * 64];        // 8 KB
  __shared__ bf16_t Ks[2][128 * 64];    // 32 KB (double-buffered)
  __shared__ bf16_t Vs[64 * 128];       // 16 KB
  __shared__ bf16_t Ps[4][16 * 128];    // 16 KB
  const int tid = threadIdx.x;
  const int wid = tid >> 6, lane = tid & 63;
  const int m16 = lane & 15, quad = lane >> 4;
  const int id = blockIdx.x;
  const int bh = (id & 7) * 8 + ((id >> 3) & 7);
  const int qt = id >> 6;
  const int b = bh >> 4, h = bh & 15;
  const size_t qbase = ((size_t)(b * 1024 + qt * 64)) * 1024 + h * 64;
  const size_t kbase = ((size_t)(b * 1024)) * 1024 + h * 64;
  const size_t vbase = ((size_t)bh * 64) * 1024;
  #pragma unroll
  for (int i = 0; i < 2; ++i) {
    int ci = i * 256 + tid;
    int row = ci >> 3, cc = ci & 7;
    *(bf16x8*)&Qs[row * 64 + ((cc ^ (row & 7)) * 8)] =
        *(const bf16x8*)&Q[qbase + (size_t)row * 1024 + cc * 8];
  }
  stage_swz<128, 64, 256>(Kb + kbase, 1024, Ks[0], tid);
  asm volatile("s_waitcnt vmcnt(0)" ::: "memory");
  __syncthreads();
  const int qm = wid * 16 + m16;
  bf16x8 qf0 = *(const bf16x8*)&Qs[qm * 64 + ((quad ^ (qm & 7)) * 8)];
  bf16x8 qf1 = *(const bf16x8*)&Qs[qm * 64 + (((4 + quad) ^ (qm & 7)) * 8)];
  floatx4 oacc[4];
  float rs[4];
  const floatx4 vzero = {0.f, 0.f, 0.f, 0.f};
  #pragma unroll
  for (int dt = 0; dt < 4; ++dt) oacc[dt] = vzero;
  #pragma unroll
  for (int r = 0; r < 4; ++r) rs[r] = 0.f;
  for (int kt = 0; kt < 8; ++kt) {
    stage_swz<64, 128, 256>(Vt + vbase + kt * 128, 1024, Vs, tid);
    if (kt < 7)
      stage_swz<128, 64, 256>(Kb + kbase + (size_t)(kt + 1) * 128 * 1024, 1024, Ks[(kt + 1) & 1], tid);
    const bf16_t* Kc = Ks[kt & 1];
    floatx4 sa[8];
    #pragma unroll
    for (int nt = 0; nt < 8; ++nt) sa[nt] = vzero;
    #pragma unroll
    for (int nt = 0; nt < 8; ++nt) {
      const int n = nt * 16 + m16;
      bf16x8 kf0 = *(const bf16x8*)&Kc[n * 64 + ((quad ^ (n & 7)) * 8)];
      bf16x8 kf1 = *(const bf16x8*)&Kc[n * 64 + (((4 + quad) ^ (n & 7)) * 8)];
      sa[nt] = __builtin_amdgcn_mfma_f32_16x16x32_bf16(qf0, kf0, sa[nt], 0, 0, 0);
      sa[nt] = __builtin_amdgcn_mfma_f32_16x16x32_bf16(qf1, kf1, sa[nt], 0, 0, 0);
    }
    #pragma unroll
    for (int nt = 0; nt < 8; ++nt)
      #pragma unroll
      for (int r = 0; r < 4; ++r) {
        float pv = __expf(sa[nt][r]);
        rs[r] += pv;
        const int prow = quad * 4 + r;
        const int g = nt * 2 + (m16 >> 3);
        const int gs = (g & 8) | ((g & 7) ^ (prow & 7));
        Ps[wid][prow * 128 + gs * 8 + (m16 & 7)] = (bf16_t)pv;
      }
    asm volatile("s_waitcnt vmcnt(0)" ::: "memory");
    __syncthreads();
    bf16x8 pf[4];
    #pragma unroll
    for (int ksub = 0; ksub < 4; ++ksub) {
      const int g = ksub * 4 + quad;
      const int gs = (g & 8) | ((g & 7) ^ (m16 & 7));
      pf[ksub] = *(const bf16x8*)&Ps[wid][m16 * 128 + gs * 8];
    }
    #pragma unroll
    for (int dt = 0; dt < 4; ++dt) {
      const int n = dt * 16 + m16;
      #pragma unroll
      for (int ksub = 0; ksub < 4; ++ksub) {
        const int g = ksub * 4 + quad;
        const int gs = (g & 8) | ((g & 7) ^ (n & 7));
        bf16x8 vf = *(const bf16x8*)&Vs[n * 128 + gs * 8];
        oacc[dt] = __builtin_amdgcn_mfma_f32_16x16x32_bf16(pf[ksub], vf, oacc[dt], 0, 0, 0);
      }
    }
    __syncthreads();
  }
  #pragma unroll
  for (int r = 0; r < 4; ++r) {
    rs[r] += __shfl_xor(rs[r], 1);
    rs[r] += __shfl_xor(rs[r], 2);
    rs[r] += __shfl_xor(rs[r], 4);
    rs[r] += __shfl_xor(rs[r], 8);
  }
  const size_t obase = ((size_t)(b * 1024 + qt * 64 + wid * 16)) * 1024 + h * 64;
  #pragma unroll
  for (int dt = 0; dt < 4; ++dt)
    #pragma unroll
    for (int r = 0; r < 4; ++r)
      O[obase + (size_t)(quad * 4 + r) * 1024 + dt * 16 + m16] = (bf16_t)(oacc[dt][r] / rs[r]);
}

// ---------------- segmented fp32 -> bf16 conversion (inputs stage) ----------------
struct Segs {
  const float* s[5];
  bf16_t* d[5];
  int n8[5];
};
__global__ __launch_bounds__(256)
void conv_multi(Segs sg) {
  const int zz = blockIdx.z;
  conv_f32_bf16(sg.s[zz], sg.d[zz], sg.n8[zz],
                blockIdx.x * 256 + threadIdx.x, gridDim.x * 256);
}

// ---------------- LN1 (p0+p1+resid) + fused W1 fp32->bf16 conversion ----------------
// Blocks [0,1024): LN rows. Blocks [1024,2048): conv W1 -> w1dst (vt region,
// V^T dead after attn; disjoint from LN's reads outlo/kb/xb and write outhi).
__global__ __launch_bounds__(256)
void ln_combine(const bf16_t* __restrict__ p0, const bf16_t* __restrict__ p1,
                const bf16_t* __restrict__ resid,
                const float* __restrict__ g, const float* __restrict__ b,
                bf16_t* __restrict__ out,
                const float* __restrict__ w1src, bf16_t* __restrict__ w1dst) {
  if (blockIdx.x >= 1024) {
    const int n8 = (int)((size_t)4096 * 1024 / 8);
    conv_f32_bf16(w1src, w1dst, n8, (blockIdx.x - 1024) * 256 + threadIdx.x, 1024 * 256);
    return;
  }
  const int row = blockIdx.x * 4 + (threadIdx.x >> 6);
  const int lane = threadIdx.x & 63;
  const size_t base = (size_t)row * 1024 + lane * 16;
  bf16x8 a0 = *(const bf16x8*)&p0[base];
  bf16x8 a1 = *(const bf16x8*)&p0[base + 8];
  bf16x8 b0 = *(const bf16x8*)&p1[base];
  bf16x8 b1 = *(const bf16x8*)&p1[base + 8];
  bf16x8 c0 = *(const bf16x8*)&resid[base];
  bf16x8 c1 = *(const bf16x8*)&resid[base + 8];
  float f[16];
  #pragma unroll
  for (int j = 0; j < 8; ++j) {
    f[j]     = (float)a0[j] + (float)b0[j] + (float)c0[j];
    f[8 + j] = (float)a1[j] + (float)b1[j] + (float)c1[j];
  }
  float s = 0.f, ss = 0.f;
  #pragma unroll
  for (int j = 0; j < 16; ++j) { s += f[j]; ss += f[j] * f[j]; }
  #pragma unroll
  for (int off = 1; off < 64; off <<= 1) { s += __shfl_xor(s, off); ss += __shfl_xor(ss, off); }
  const float m = s * (1.f / 1024.f);
  const float inv_sd = rsqrtf(ss * (1.f / 1024.f) - m * m + 1e-5f);
  const float* gp = g + lane * 16;
  const float* bp = b + lane * 16;
  bf16x8 o0, o1;
  #pragma unroll
  for (int j = 0; j < 8; ++j) o0[j] = (bf16_t)((f[j] - m) * inv_sd * gp[j] + bp[j]);
  #pragma unroll
  for (int j = 0; j < 8; ++j) o1[j] = (bf16_t)((f[8 + j] - m) * inv_sd * gp[8 + j] + bp[8 + j]);
  *(bf16x8*)&out[base] = o0;
  *(bf16x8*)&out[base + 8] = o1;
}

// ---- fused: (W2 combine + b2 + resid) -> LN2 -> x2; quantum -> z; ql2w conv ----
__global__ __launch_bounds__(256)
void ln2_quantum(const bf16_t* __restrict__ p0, const bf16_t* __restrict__ p1,
                 const bf16_t* __restrict__ resid, const float* __restrict__ bias,
                 const float* __restrict__ g, const float* __restrict__ b,
                 bf16_t* __restrict__ x2,
                 const float* __restrict__ qw1, const float* __restrict__ qb1,
                 const float* __restrict__ qwt, bf16_t* __restrict__ zout,
                 const float* __restrict__ ql2w, bf16_t* __restrict__ ql2wb) {
  if (blockIdx.z == 1) {
    const int n8 = 1024 * 1032 / 8;
    conv_f32_bf16(ql2w, ql2wb, n8, blockIdx.x * 256 + threadIdx.x, gridDim.x * 256);
    return;
  }
  const int row = blockIdx.x * 4 + (threadIdx.x >> 6);
  const int lane = threadIdx.x & 63;
  const size_t base = (size_t)row * 1024 + lane * 16;
  bf16x8 a0 = *(const bf16x8*)&p0[base];
  bf16x8 a1 = *(const bf16x8*)&p0[base + 8];
  bf16x8 b0 = *(const bf16x8*)&p1[base];
  bf16x8 b1 = *(const bf16x8*)&p1[base + 8];
  bf16x8 c0 = *(const bf16x8*)&resid[base];
  bf16x8 c1 = *(const bf16x8*)&resid[base + 8];
  const float* bsp = bias + lane * 16;
  float f[16];
  #pragma unroll
  for (int j = 0; j < 8; ++j) {
    f[j]     = (float)a0[j] + (float)b0[j] + (float)c0[j] + bsp[j];
    f[8 + j] = (float)a1[j] + (float)b1[j] + (float)c1[j] + bsp[8 + j];
  }
  float s = 0.f, ss = 0.f;
  #pragma unroll
  for (int j = 0; j < 16; ++j) { s += f[j]; ss += f[j] * f[j]; }
  #pragma unroll
  for (int off = 1; off < 64; off <<= 1) { s += __shfl_xor(s, off); ss += __shfl_xor(ss, off); }
  const float m = s * (1.f / 1024.f);
  const float inv_sd = rsqrtf(ss * (1.f / 1024.f) - m * m + 1e-5f);
  const float* gp = g + lane * 16;
  const float* bp = b + lane * 16;
  bf16x8 o0, o1;
  #pragma unroll
  for (int j = 0; j < 8; ++j) o0[j] = (bf16_t)((f[j] - m) * inv_sd * gp[j] + bp[j]);
  #pragma unroll
  for (int j = 0; j < 8; ++j) o1[j] = (bf16_t)((f[8 + j] - m) * inv_sd * gp[8 + j] + bp[8 + j]);
  *(bf16x8*)&x2[base] = o0;
  *(bf16x8*)&x2[base + 8] = o1;
  float th[8];
  #pragma unroll
  for (int qq = 0; qq < 8; ++qq) {
    const float* wp = qw1 + (size_t)qq * 1024 + lane * 16;
    float sdot = 0.f;
    #pragma unroll
    for (int j = 0; j < 8; ++j)
      sdot += (float)o0[j] * wp[j] + (float)o1[j] * wp[8 + j];
    #pragma unroll
    for (int off = 1; off < 64; off <<= 1) sdot += __shfl_xor(sdot, off);
    th[qq] = sdot + qb1[qq] + qwt[qq];
  }
  if (lane == 0) {
    float c[8];
    #pragma unroll
    for (int qq = 0; qq < 8; ++qq) c[qq] = cosf(th[qq]);
    float z0 = 1.f;
    #pragma unroll
    for (int u = 1; u < 8; ++u) z0 *= c[u];
    zout[(size_t)row * 8 + 0] = (bf16_t)z0;
    float pp = c[0];
    #pragma unroll
    for (int w = 1; w < 8; ++w) { pp *= c[w]; zout[(size_t)row * 8 + w] = (bf16_t)pp; }
  }
}

extern "C" void kernel_launch(void* const* d_in, const int* in_sizes, int n_in,
                              void* d_out, int out_size, void* d_ws, size_t ws_size,
                              hipStream_t stream) {
  const float* x    = (const float*)d_in[0];
  const float* Wq   = (const float*)d_in[1];
  const float* Wk   = (const float*)d_in[2];
  const float* Wv   = (const float*)d_in[3];
  const float* Wo   = (const float*)d_in[4];
  const float* ln1g = (const float*)d_in[5];
  const float* ln1b = (const float*)d_in[6];
  const float* W1   = (const float*)d_in[7];
  const float* b1   = (const float*)d_in[8];
  const float* W2   = (const float*)d_in[9];
  const float* b2   = (const float*)d_in[10];
  const float* ln2g = (const float*)d_in[11];
  const float* ln2b = (const float*)d_in[12];
  const float* qw1  = (const float*)d_in[13];
  const float* qb1  = (const float*)d_in[14];
  const float* qwt  = (const float*)d_in[15];
  const float* ql2w = (const float*)d_in[16];
  const float* ql2b = (const float*)d_in[17];
  bf16_t* ws = (bf16_t*)d_ws;

  const size_t T = (size_t)4096 * 1024;
  const size_t M1 = (size_t)1024 * 1024;
  bf16_t* outlo = (bf16_t*)d_out;
  bf16_t* outhi = outlo + T;

  bf16_t* xb    = ws;            // x bf16; resid for LN1; then W2 partial p0
  bf16_t* kb    = ws + T;        // K; Wo partial p1; then w2b; then z
  bf16_t* vt    = ws + 2 * T;    // V^T; then w1b; then W2 partial p1 / x2
  bf16_t* ff    = ws + 3 * T;    // wqkvb+wob; then FFN hidden; then ql2wb
  bf16_t* wqkvb = ff;
  bf16_t* wob   = ff + 3 * M1;
  bf16_t* w1b   = vt;
  bf16_t* w2b   = kb;
  bf16_t* ql2wb = ff;
  bf16_t* q     = outlo;
  bf16_t* o     = outhi;
  bf16_t* x1    = outhi;         // LN1 out (o dead)
  bf16_t* x2    = vt;            // LN2 out (in-place over W2 p1)
  bf16_t* z     = kb;

  {
    Segs sg;
    sg.s[0] = x;  sg.d[0] = xb;            sg.n8[0] = (int)(T / 8);
    sg.s[1] = Wq; sg.d[1] = wqkvb;         sg.n8[1] = (int)(M1 / 8);
    sg.s[2] = Wk; sg.d[2] = wqkvb + M1;    sg.n8[2] = (int)(M1 / 8);
    sg.s[3] = Wv; sg.d[3] = wqkvb + 2*M1;  sg.n8[3] = (int)(M1 / 8);
    sg.s[4] = Wo; sg.d[4] = wob;           sg.n8[4] = (int)(M1 / 8);
    conv_multi<<<dim3(512, 1, 5), 256, 0, stream>>>(sg);
  }
  gemm_qkv<<<192, 512, 0, stream>>>(xb, wqkvb, q, kb, vt);
  attn_kernel<<<1024, 256, 0, stream>>>(q, kb, vt, o);
  // Wo split-K=2 on 128x128 tile: partials outlo (q dead) + kb (K dead).
  gemm128_sk<<<512, 256, 0, stream>>>(o, wob, outlo, kb, 1024, 1024, 1024, 32, 8);
  // LN1 (reads outlo,kb,xb; writes x1) + fused W1 conversion into vt (dead).
  ln_combine<<<2048, 256, 0, stream>>>(outlo, kb, xb, ln1g, ln1b, x1, W1, w1b);
  // W1 GEMM (reads x1, w1b; writes ff) + fused W2 conversion into kb (p1 dead,
  // w2b needed by the next launch); conv hides under the GEMM tail.
  gemm256<EPI_BIAS_RELU><<<512, 512, 0, stream>>>(x1, w1b, ff, b1, 4096, 1024, 16, 16, W2, w2b);
  // W2 split-K=2 on 128x128 tile: partials xb (x dead) + vt (w1b dead).
  gemm128_sk<<<512, 256, 0, stream>>>(ff, w2b, xb, vt, 1024, 4096, 4096, 32, 8);
  ln2_quantum<<<dim3(1024, 1, 2), 256, 0, stream>>>(
      xb, vt, x1, b2, ln2g, ln2b, x2, qw1, qb1, qwt, z, ql2w, ql2wb);
  gemm64p<<<512, 256, 0, stream>>>(x2, ql2wb, (float*)d_out, ql2b, z, ql2w);
}

// Round 12
// 364.493 us; speedup vs baseline: 1.0262x; 1.0038x over previous
//
#include <hip/hip_runtime.h>
#include <hip/hip_bf16.h>

typedef __bf16 bf16_t;
typedef __attribute__((ext_vector_type(8))) __bf16 bf16x8;
typedef __attribute__((ext_vector_type(4))) float floatx4;

#define BM 128

enum { EPI_NONE = 0, EPI_RESID, EPI_BIAS_RELU, EPI_BIAS_RESID, EPI_QL2, EPI_PART };

__device__ __forceinline__ void gld_lds16(const bf16_t* g, bf16_t* l) {
  __builtin_amdgcn_global_load_lds(
      (__attribute__((address_space(1))) void*)(g),
      (__attribute__((address_space(3))) void*)(l), 16, 0, 0);
}

// Swizzled DMA staging: LDS slot ci=(row,cc) receives GLOBAL granule cc^(row&7).
template<int ROWS, int COLS, int NTHR>
__device__ __forceinline__ void stage_swz(const bf16_t* g, int ld, bf16_t* lds, int tid) {
  constexpr int G = COLS / 8;
  #pragma unroll
  for (int i = 0; i < ROWS * G / NTHR; ++i) {
    int ci = i * NTHR + tid;
    int row = ci / G, cc = ci % G;
    int gg = (G == 8) ? (cc ^ (row & 7)) : ((cc & 8) | ((cc & 7) ^ (row & 7)));
    gld_lds16(g + (size_t)row * ld + gg * 8, lds + ci * 8);
  }
}

// XCD-chunked bijective remap (nwg must be a multiple of 8).
__device__ __forceinline__ int xcd_remap(int id, int nwg) {
  return (id & 7) * (nwg >> 3) + (id >> 3);
}

// fp32 -> bf16 conversion helper (grid-stride over n8 bf16x8 items)
__device__ __forceinline__ void conv_f32_bf16(const float* in, bf16_t* out,
                                              int n8, int idx, int stride) {
  for (int i = idx; i < n8; i += stride) {
    const float* p = in + (size_t)i * 8;
    floatx4 a = *(const floatx4*)p;
    floatx4 b = *(const floatx4*)(p + 4);
    bf16x8 o;
    #pragma unroll
    for (int j = 0; j < 4; ++j) { o[j] = (bf16_t)a[j]; o[4 + j] = (bf16_t)b[j]; }
    *(bf16x8*)(out + (size_t)i * 8) = o;
  }
}

// ======== R2-proven core: 128x128 tile, BK=64, double-buffered LDS,
// prefetch issued BEFORE compute, vmcnt(0)+__syncthreads at end of step.
__device__ __forceinline__ void core128(const bf16_t* __restrict__ Ag,
                                        const bf16_t* __restrict__ Bg,
                                        int Kloop, int lda, int ldb,
                                        bf16_t* As, bf16_t* Bs,
                                        floatx4 acc[4][4]) {
  const int tid = threadIdx.x;
  const int wid = tid >> 6, lane = tid & 63;
  const int wm = (wid >> 1) * 64, wn = (wid & 1) * 64;
  const int m16 = lane & 15, quad = lane >> 4;
  const int r7 = m16 & 7;
  constexpr int BUF = BM * 64;
  stage_swz<128, 64, 256>(Ag, lda, As, tid);
  stage_swz<128, 64, 256>(Bg, ldb, Bs, tid);
  asm volatile("s_waitcnt vmcnt(0)" ::: "memory");
  __syncthreads();
  int cur = 0;
  for (int k0 = 0; k0 < Kloop; k0 += 64) {
    if (k0 + 64 < Kloop) {
      stage_swz<128, 64, 256>(Ag + k0 + 64, lda, As + (cur ^ 1) * BUF, tid);
      stage_swz<128, 64, 256>(Bg + k0 + 64, ldb, Bs + (cur ^ 1) * BUF, tid);
    }
    const bf16_t* Ab = As + cur * BUF;
    const bf16_t* Bb = Bs + cur * BUF;
    #pragma unroll
    for (int ks = 0; ks < 2; ++ks) {
      const int gi = ks * 4 + quad;
      const int slot = gi ^ r7;
      bf16x8 af[4], bfr[4];
      #pragma unroll
      for (int mt = 0; mt < 4; ++mt)
        af[mt] = *(const bf16x8*)&Ab[((wm + mt * 16 + m16) * 8 + slot) * 8];
      #pragma unroll
      for (int nt = 0; nt < 4; ++nt)
        bfr[nt] = *(const bf16x8*)&Bb[((wn + nt * 16 + m16) * 8 + slot) * 8];
      #pragma unroll
      for (int mt = 0; mt < 4; ++mt)
        #pragma unroll
        for (int nt = 0; nt < 4; ++nt)
          acc[mt][nt] = __builtin_amdgcn_mfma_f32_16x16x32_bf16(af[mt], bfr[nt], acc[mt][nt], 0, 0, 0);
    }
    asm volatile("s_waitcnt vmcnt(0)" ::: "memory");
    __syncthreads();
    cur ^= 1;
  }
}

// ======== 8-phase core (m201 template port): 256x256, BK=64, 8 waves.
// Phase order per K-tile: (ks0,A0),(ks1,A0),(ks0,A1),(ks1,A1); B frags read in
// P0/P1 and HELD in regs for P2/P3 -> A0,B0,B1 of current buffer dead after P1,
// A1 dead after P3. Tile t+2 stages into those dead regions of the CURRENT
// buffer: (t,P2): A0+B0; (t,P3): B1; (t+1,P0): A1. Every load issued >=7 phases
// before its first read. One counted vmcnt(6) per tile boundary.
__device__ __forceinline__ void core256_8ph(const bf16_t* __restrict__ Ag,
                                            const bf16_t* __restrict__ Bg,
                                            int Kloop, int lda, int ldb,
                                            bf16_t* As, bf16_t* Bs,
                                            floatx4 acc[8][4]) {
  const int tid = threadIdx.x;
  const int wid = tid >> 6, lane = tid & 63;
  const int wmh = ((wid >> 2) & 1) * 64;  // wave row offset inside each 128-half
  const int wn = (wid & 3) * 64;
  const int m16 = lane & 15, quad = lane >> 4;
  const int r7 = m16 & 7;
  constexpr int BUF = 256 * 64;
  constexpr int HALF = 128 * 64;
  const int NT = Kloop >> 6;
  // prologue: tile0 {A0,B0,B1,A1}, tile1 {A0,B0,B1}; wait tile0 (oldest 8 of 14)
  stage_swz<128, 64, 512>(Ag, lda, As, tid);
  stage_swz<128, 64, 512>(Bg, ldb, Bs, tid);
  stage_swz<128, 64, 512>(Bg + (size_t)128 * ldb, ldb, Bs + HALF, tid);
  stage_swz<128, 64, 512>(Ag + (size_t)128 * lda, lda, As + HALF, tid);
  stage_swz<128, 64, 512>(Ag + 64, lda, As + BUF, tid);
  stage_swz<128, 64, 512>(Bg + 64, ldb, Bs + BUF, tid);
  stage_swz<128, 64, 512>(Bg + 64 + (size_t)128 * ldb, ldb, Bs + BUF + HALF, tid);
  asm volatile("s_waitcnt vmcnt(6)" ::: "memory");
  asm volatile("s_barrier" ::: "memory");
  for (int t = 0; t < NT; ++t) {
    const int bt = (t & 1) * BUF;
    const int bn = bt ^ BUF;
    const bf16_t* Ab = As + bt;
    const bf16_t* Bb = Bs + bt;
    bf16x8 bfr0[4], bfr1[4], af[4];
    // ---- P0: (ks0, A0); stage (t+1)A1 -> other buffer ----
    #pragma unroll
    for (int nt = 0; nt < 4; ++nt)
      bfr0[nt] = *(const bf16x8*)&Bb[((wn + nt * 16 + m16) * 8 + (quad ^ r7)) * 8];
    #pragma unroll
    for (int j = 0; j < 4; ++j)
      af[j] = *(const bf16x8*)&Ab[((wmh + j * 16 + m16) * 8 + (quad ^ r7)) * 8];
    if (t + 1 < NT)
      stage_swz<128, 64, 512>(Ag + (size_t)(t + 1) * 64 + (size_t)128 * lda, lda,
                              As + bn + HALF, tid);
    asm volatile("s_barrier" ::: "memory");
    __builtin_amdgcn_s_setprio(1);
    #pragma unroll
    for (int j = 0; j < 4; ++j)
      #pragma unroll
      for (int nt = 0; nt < 4; ++nt)
        acc[j][nt] = __builtin_amdgcn_mfma_f32_16x16x32_bf16(af[j], bfr0[nt], acc[j][nt], 0, 0, 0);
    __builtin_amdgcn_s_setprio(0);
    asm volatile("s_barrier" ::: "memory");
    // ---- P1: (ks1, A0) ----
    #pragma unroll
    for (int nt = 0; nt < 4; ++nt)
      bfr1[nt] = *(const bf16x8*)&Bb[((wn + nt * 16 + m16) * 8 + ((4 + quad) ^ r7)) * 8];
    #pragma unroll
    for (int j = 0; j < 4; ++j)
      af[j] = *(const bf16x8*)&Ab[((wmh + j * 16 + m16) * 8 + ((4 + quad) ^ r7)) * 8];
    asm volatile("s_barrier" ::: "memory");
    __builtin_amdgcn_s_setprio(1);
    #pragma unroll
    for (int j = 0; j < 4; ++j)
      #pragma unroll
      for (int nt = 0; nt < 4; ++nt)
        acc[j][nt] = __builtin_amdgcn_mfma_f32_16x16x32_bf16(af[j], bfr1[nt], acc[j][nt], 0, 0, 0);
    __builtin_amdgcn_s_setprio(0);
    asm volatile("s_barrier" ::: "memory");
    // ---- P2: (ks0, A1); stage (t+2){A0,B0} into CURRENT buffer's dead regions ----
    #pragma unroll
    for (int j = 0; j < 4; ++j)
      af[j] = *(const bf16x8*)&Ab[((128 + wmh + j * 16 + m16) * 8 + (quad ^ r7)) * 8];
    if (t + 2 < NT) {
      stage_swz<128, 64, 512>(Ag + (size_t)(t + 2) * 64, lda, As + bt, tid);
      stage_swz<128, 64, 512>(Bg + (size_t)(t + 2) * 64, ldb, Bs + bt, tid);
    }
    asm volatile("s_barrier" ::: "memory");
    __builtin_amdgcn_s_setprio(1);
    #pragma unroll
    for (int j = 0; j < 4; ++j)
      #pragma unroll
      for (int nt = 0; nt < 4; ++nt)
        acc[4 + j][nt] = __builtin_amdgcn_mfma_f32_16x16x32_bf16(af[j], bfr0[nt], acc[4 + j][nt], 0, 0, 0);
    __builtin_amdgcn_s_setprio(0);
    asm volatile("s_barrier" ::: "memory");
    // ---- P3: (ks1, A1); stage (t+2)B1 ----
    #pragma unroll
    for (int j = 0; j < 4; ++j)
      af[j] = *(const bf16x8*)&Ab[((128 + wmh + j * 16 + m16) * 8 + ((4 + quad) ^ r7)) * 8];
    if (t + 2 < NT)
      stage_swz<128, 64, 512>(Bg + (size_t)(t + 2) * 64 + (size_t)128 * ldb, ldb,
                              Bs + bt + HALF, tid);
    asm volatile("s_barrier" ::: "memory");
    __builtin_amdgcn_s_setprio(1);
    #pragma unroll
    for (int j = 0; j < 4; ++j)
      #pragma unroll
      for (int nt = 0; nt < 4; ++nt)
        acc[4 + j][nt] = __builtin_amdgcn_mfma_f32_16x16x32_bf16(af[j], bfr1[nt], acc[4 + j][nt], 0, 0, 0);
    __builtin_amdgcn_s_setprio(0);
    // ---- boundary: counted wait, (t+2)'s loads stay in flight ----
    if (t + 1 < NT) {
      if (t + 2 < NT) asm volatile("s_waitcnt vmcnt(6)" ::: "memory");
      else            asm volatile("s_waitcnt vmcnt(0)" ::: "memory");
    }
    asm volatile("s_barrier" ::: "memory");
  }
}

// ---- 256x256 bf16 GEMM (W1: bias+relu) + fused W2 fp32->bf16 conversion.
// Blocks [0,256): GEMM (XCD-chunked + GROUP_M=8). Blocks [256,512): conv W2
// into w2dst (kb region; p1 consumed by previous launch, w2b needed by next).
template<int EPI>
__global__ __launch_bounds__(512)
void gemm256(const bf16_t* __restrict__ A, const bf16_t* __restrict__ B,
             bf16_t* __restrict__ C, const float* __restrict__ bias,
             int N, int K, int mblocks, int nblocks,
             const float* __restrict__ w2src, bf16_t* __restrict__ w2dst) {
  __shared__ bf16_t As[2 * 256 * 64];   // 64 KB
  __shared__ bf16_t Bs[2 * 256 * 64];   // 64 KB
  const int tid = threadIdx.x;
  if (blockIdx.x >= 256) {
    const int n8 = (int)((size_t)4096 * 1024 / 8);
    conv_f32_bf16(w2src, w2dst, n8, (blockIdx.x - 256) * 512 + tid, 256 * 512);
    return;
  }
  const int wid = tid >> 6, lane = tid & 63;
  const int wmh = ((wid >> 2) & 1) * 64, wn = (wid & 3) * 64;
  const int m16 = lane & 15, quad = lane >> 4;
  const int id = xcd_remap(blockIdx.x, 256);
  const int per_group = 8 * nblocks;
  const int grp = id / per_group, rem = id % per_group;
  const int m0 = (grp * 8 + (rem & 7)) * 256;
  const int n0 = (rem >> 3) * 256;
  floatx4 acc[8][4];
  const floatx4 vzero = {0.f, 0.f, 0.f, 0.f};
  #pragma unroll
  for (int mt = 0; mt < 8; ++mt)
    #pragma unroll
    for (int nt = 0; nt < 4; ++nt) acc[mt][nt] = vzero;
  core256_8ph(A + (size_t)m0 * K, B + (size_t)n0 * K, K, K, K, As, Bs, acc);
  // 8-phase layout: acc[mh*4+j] covers rows mh*128 + wmh + j*16 (+quad*4+r)
  #pragma unroll
  for (int mh = 0; mh < 2; ++mh)
    #pragma unroll
    for (int j = 0; j < 4; ++j)
      #pragma unroll
      for (int nt = 0; nt < 4; ++nt) {
        const int gcol = n0 + wn + nt * 16 + m16;
        float bv = (EPI == EPI_BIAS_RELU) ? bias[gcol] : 0.f;
        #pragma unroll
        for (int r = 0; r < 4; ++r) {
          const int grow = m0 + mh * 128 + wmh + j * 16 + quad * 4 + r;
          float v = acc[mh * 4 + j][nt][r];
          if (EPI == EPI_BIAS_RELU) { v += bv; v = fmaxf(v, 0.f); }
          C[(size_t)grow * N + gcol] = (bf16_t)v;
        }
      }
}

// ---- fused QKV on 8-phase core + fused Wo fp32->bf16 conversion.
// Blocks [0,192): GEMM (grid-fill 75%); blocks [192,256): conv Wo -> wodst
// (ff+3M1; disjoint from wqkvb reads and q/kb/vt writes; wob consumed 2
// launches later by gemm128_sk). Conv runs on the otherwise-idle quarter.
__global__ __launch_bounds__(512)
void gemm_qkv(const bf16_t* __restrict__ X, const bf16_t* __restrict__ Wb,
              bf16_t* __restrict__ Qo, bf16_t* __restrict__ Ko, bf16_t* __restrict__ Vt,
              const float* __restrict__ wosrc, bf16_t* __restrict__ wodst) {
  __shared__ bf16_t As[2 * 256 * 64];
  __shared__ bf16_t Bs[2 * 256 * 64];
  const int tid = threadIdx.x;
  if (blockIdx.x >= 192) {
    const int n8 = (int)((size_t)1024 * 1024 / 8);
    conv_f32_bf16(wosrc, wodst, n8, (blockIdx.x - 192) * 512 + tid, 64 * 512);
    return;
  }
  const int wid = tid >> 6, lane = tid & 63;
  const int wmh = ((wid >> 2) & 1) * 64, wn = (wid & 3) * 64;
  const int m16 = lane & 15, quad = lane >> 4;
  const int id = xcd_remap(blockIdx.x, 192);
  const int per_group = 8 * 12;            // GROUP_M=8 x (4 nblocks * 3 sel)
  const int grp = id / per_group, rem = id % per_group;
  const int m0 = (grp * 8 + (rem & 7)) * 256;
  const int nall = rem >> 3;               // 0..11
  const int n0 = (nall & 3) * 256;
  const int sel = nall >> 2;
  const bf16_t* B = Wb + (size_t)sel * 1024 * 1024;
  floatx4 acc[8][4];
  const floatx4 vzero = {0.f, 0.f, 0.f, 0.f};
  #pragma unroll
  for (int mt = 0; mt < 8; ++mt)
    #pragma unroll
    for (int nt = 0; nt < 4; ++nt) acc[mt][nt] = vzero;
  core256_8ph(X + (size_t)m0 * 1024, B + (size_t)n0 * 1024, 1024, 1024, 1024, As, Bs, acc);
  // 8-phase layout: acc[mh*4+j] covers rows mh*128 + wmh + j*16 (+quad*4+r)
  if (sel < 2) {
    bf16_t* C = sel ? Ko : Qo;
    const float sc = sel ? 1.f : 0.125f;
    #pragma unroll
    for (int mh = 0; mh < 2; ++mh)
      #pragma unroll
      for (int j = 0; j < 4; ++j)
        #pragma unroll
        for (int nt = 0; nt < 4; ++nt) {
          const int gcol = n0 + wn + nt * 16 + m16;
          #pragma unroll
          for (int r = 0; r < 4; ++r) {
            const int grow = m0 + mh * 128 + wmh + j * 16 + quad * 4 + r;
            C[(size_t)grow * 1024 + gcol] = (bf16_t)(acc[mh * 4 + j][nt][r] * sc);
          }
        }
  } else {
    #pragma unroll
    for (int mh = 0; mh < 2; ++mh)
      #pragma unroll
      for (int j = 0; j < 4; ++j) {
        const int grow0 = m0 + mh * 128 + wmh + j * 16 + quad * 4;
        const int b = grow0 >> 10, s = grow0 & 1023;
        #pragma unroll
        for (int nt = 0; nt < 4; ++nt) {
          const int gcol = n0 + wn + nt * 16 + m16;
          const int h = gcol >> 6, d = gcol & 63;
          #pragma unroll
          for (int r = 0; r < 4; ++r)
            Vt[(((size_t)b * 16 + h) * 64 + d) * 1024 + s + r] = (bf16_t)acc[mh * 4 + j][nt][r];
        }
      }
  }
}

// ---- 128x128 split-K=2; R2-proven core; XCD-chunked, GROUP_M=8 (Wo, W2) ----
__global__ __launch_bounds__(256)
void gemm128_sk(const bf16_t* __restrict__ A, const bf16_t* __restrict__ B,
                bf16_t* __restrict__ p0, bf16_t* __restrict__ p1,
                int N, int K, int ldb, int mblocks, int nblocks) {
  __shared__ bf16_t As[2 * BM * 64];
  __shared__ bf16_t Bs[2 * BM * 64];
  const int tid = threadIdx.x;
  const int wid = tid >> 6, lane = tid & 63;
  const int wm = (wid >> 1) * 64, wn = (wid & 1) * 64;
  const int m16 = lane & 15, quad = lane >> 4;
  const int id = xcd_remap(blockIdx.x, gridDim.x);
  const int per_kh = mblocks * nblocks;
  const int kh = id / per_kh;
  const int rem2 = id % per_kh;
  const int per_group = 8 * nblocks;
  const int grp = rem2 / per_group, rem = rem2 % per_group;
  const int m0 = (grp * 8 + (rem & 7)) * BM;
  const int n0 = (rem >> 3) * BM;
  const int Keff = K / 2;
  floatx4 acc[4][4];
  const floatx4 vzero = {0.f, 0.f, 0.f, 0.f};
  #pragma unroll
  for (int mt = 0; mt < 4; ++mt)
    #pragma unroll
    for (int nt = 0; nt < 4; ++nt) acc[mt][nt] = vzero;
  core128(A + (size_t)m0 * K + (size_t)kh * Keff,
          B + (size_t)n0 * ldb + (size_t)kh * Keff, Keff, K, ldb, As, Bs, acc);
  bf16_t* Cp = kh ? p1 : p0;
  #pragma unroll
  for (int mt = 0; mt < 4; ++mt)
    #pragma unroll
    for (int nt = 0; nt < 4; ++nt) {
      const int gcol = n0 + wn + nt * 16 + m16;
      #pragma unroll
      for (int r = 0; r < 4; ++r) {
        const int grow = m0 + wm + mt * 16 + quad * 4 + r;
        Cp[(size_t)grow * N + gcol] = (bf16_t)acc[mt][nt][r];
      }
    }
}

// ======== ql2 final GEMM: 128x64 tile, BK=64, R2-pipelined, 512 blocks (2/CU),
// 48 KB LDS; QL2 epilogue (bias + z-dot), fp32 out ========
__global__ __launch_bounds__(256)
void gemm64p(const bf16_t* __restrict__ A, const bf16_t* __restrict__ B,
             float* __restrict__ C, const float* __restrict__ bias,
             const bf16_t* __restrict__ z, const float* __restrict__ zw) {
  __shared__ bf16_t As[2 * 128 * 64];   // 32 KB
  __shared__ bf16_t Bs[2 * 64 * 64];    // 16 KB
  const int tid = threadIdx.x;
  const int wid = tid >> 6, lane = tid & 63;
  const int wm = (wid >> 1) * 64, wn = (wid & 1) * 32;
  const int m16 = lane & 15, quad = lane >> 4;
  const int r7 = m16 & 7;
  const int id = xcd_remap(blockIdx.x, gridDim.x);
  const int per_group = 8 * 16;   // GROUP_M=8 x 16 nblocks(64-wide)
  const int grp = id / per_group, rem = id % per_group;
  const int m0 = (grp * 8 + (rem & 7)) * 128;
  const int n0 = (rem >> 3) * 64;
  // B row n = output col n: ql2wb[n*1032 + 8 + k] (first 8 are z-weights)
  const bf16_t* Ag = A + (size_t)m0 * 1024;
  const bf16_t* Bg = B + (size_t)n0 * 1032 + 8;
  constexpr int ABUF = 128 * 64, BBUF = 64 * 64;
  floatx4 acc[4][2];
  const floatx4 vzero = {0.f, 0.f, 0.f, 0.f};
  #pragma unroll
  for (int mt = 0; mt < 4; ++mt)
    #pragma unroll
    for (int nt = 0; nt < 2; ++nt) acc[mt][nt] = vzero;
  stage_swz<128, 64, 256>(Ag, 1024, As, tid);
  stage_swz<64, 64, 256>(Bg, 1032, Bs, tid);
  asm volatile("s_waitcnt vmcnt(0)" ::: "memory");
  __syncthreads();
  int cur = 0;
  for (int k0 = 0; k0 < 1024; k0 += 64) {
    if (k0 + 64 < 1024) {
      stage_swz<128, 64, 256>(Ag + k0 + 64, 1024, As + (cur ^ 1) * ABUF, tid);
      stage_swz<64, 64, 256>(Bg + k0 + 64, 1032, Bs + (cur ^ 1) * BBUF, tid);
    }
    const bf16_t* Ab = As + cur * ABUF;
    const bf16_t* Bb = Bs + cur * BBUF;
    #pragma unroll
    for (int ks = 0; ks < 2; ++ks) {
      const int slot = (ks * 4 + quad) ^ r7;
      bf16x8 af[4], bfr[2];
      #pragma unroll
      for (int mt = 0; mt < 4; ++mt)
        af[mt] = *(const bf16x8*)&Ab[((wm + mt * 16 + m16) * 8 + slot) * 8];
      #pragma unroll
      for (int nt = 0; nt < 2; ++nt)
        bfr[nt] = *(const bf16x8*)&Bb[((wn + nt * 16 + m16) * 8 + slot) * 8];
      #pragma unroll
      for (int mt = 0; mt < 4; ++mt)
        #pragma unroll
        for (int nt = 0; nt < 2; ++nt)
          acc[mt][nt] = __builtin_amdgcn_mfma_f32_16x16x32_bf16(af[mt], bfr[nt], acc[mt][nt], 0, 0, 0);
    }
    asm volatile("s_waitcnt vmcnt(0)" ::: "memory");
    __syncthreads();
    cur ^= 1;
  }
  #pragma unroll
  for (int mt = 0; mt < 4; ++mt)
    #pragma unroll
    for (int nt = 0; nt < 2; ++nt) {
      const int gcol = n0 + wn + nt * 16 + m16;
      const float bv = bias[gcol];
      #pragma unroll
      for (int r = 0; r < 4; ++r) {
        const int grow = m0 + wm + mt * 16 + quad * 4 + r;
        float s = 0.f;
        #pragma unroll
        for (int u = 0; u < 8; ++u)
          s += (float)z[(size_t)grow * 8 + u] * zw[(size_t)gcol * 1032 + u];
        C[(size_t)grow * 1024 + gcol] = acc[mt][nt][r] + bv + s;
      }
    }
}

// ======== flash attention (R6-proven): DMA K/V, 2-deep, XCD-chunked heads ========
__global__ __launch_bounds__(256)
void attn_kernel(const bf16_t* __restrict__ Q, const bf16_t* __restrict__ Kb,
                 const bf16_t* __restrict__ Vt, bf16_t* __restrict__ O) {
  __shared__ bf16_t Qs[64 * 64];        // 8 KB
  __shared__ bf16_t Ks[2][128 * 64];    // 32 KB (double-buffered)
  __shared__ bf16_t Vs[64 * 128];       // 16 KB
  __shared__ bf16_t Ps[4][16 * 128];    // 16 KB
  const int tid = threadIdx.x;
  const int wid = tid >> 6, lane = tid & 63;
  const int m16 = lane & 15, quad = lane >> 4;
  const int id = blockIdx.x;
  const int bh = (id & 7) * 8 + ((id >> 3) & 7);
  const int qt = id >> 6;
  const int b = bh >> 4, h = bh & 15;
  const size_t qbase = ((size_t)(b * 1024 + qt * 64)) * 1024 + h * 64;
  const size_t kbase = ((size_t)(b * 1024)) * 1024 + h * 64;
  const size_t vbase = ((size_t)bh * 64) * 1024;
  #pragma unroll
  for (int i = 0; i < 2; ++i) {
    int ci = i * 256 + tid;
    int row = ci >> 3, cc = ci & 7;
    *(bf16x8*)&Qs[row * 64 + ((cc ^ (row & 7)) * 8)] =
        *(const bf16x8*)&Q[qbase + (size_t)row * 1024 + cc * 8];
  }
  stage_swz<128, 64, 256>(Kb + kbase, 1024, Ks[0], tid);
  asm volatile("s_waitcnt vmcnt(0)" ::: "memory");
  __syncthreads();
  const int qm = wid * 16 + m16;
  bf16x8 qf0 = *(const bf16x8*)&Qs[qm * 64 + ((quad ^ (qm & 7)) * 8)];
  bf16x8 qf1 = *(const bf16x8*)&Qs[qm * 64 + (((4 + quad) ^ (qm & 7)) * 8)];
  floatx4 oacc[4];
  float rs[4];
  const floatx4 vzero = {0.f, 0.f, 0.f, 0.f};
  #pragma unroll
  for (int dt = 0; dt < 4; ++dt) oacc[dt] = vzero;
  #pragma unroll
  for (int r = 0; r < 4; ++r) rs[r] = 0.f;
  for (int kt = 0; kt < 8; ++kt) {
    stage_swz<64, 128, 256>(Vt + vbase + kt * 128, 1024, Vs, tid);
    if (kt < 7)
      stage_swz<128, 64, 256>(Kb + kbase + (size_t)(kt + 1) * 128 * 1024, 1024, Ks[(kt + 1) & 1], tid);
    const bf16_t* Kc = Ks[kt & 1];
    floatx4 sa[8];
    #pragma unroll
    for (int nt = 0; nt < 8; ++nt) sa[nt] = vzero;
    #pragma unroll
    for (int nt = 0; nt < 8; ++nt) {
      const int n = nt * 16 + m16;
      bf16x8 kf0 = *(const bf16x8*)&Kc[n * 64 + ((quad ^ (n & 7)) * 8)];
      bf16x8 kf1 = *(const bf16x8*)&Kc[n * 64 + (((4 + quad) ^ (n & 7)) * 8)];
      sa[nt] = __builtin_amdgcn_mfma_f32_16x16x32_bf16(qf0, kf0, sa[nt], 0, 0, 0);
      sa[nt] = __builtin_amdgcn_mfma_f32_16x16x32_bf16(qf1, kf1, sa[nt], 0, 0, 0);
    }
    #pragma unroll
    for (int nt = 0; nt < 8; ++nt)
      #pragma unroll
      for (int r = 0; r < 4; ++r) {
        float pv = __expf(sa[nt][r]);
        rs[r] += pv;
        const int prow = quad * 4 + r;
        const int g = nt * 2 + (m16 >> 3);
        const int gs = (g & 8) | ((g & 7) ^ (prow & 7));
        Ps[wid][prow * 128 + gs * 8 + (m16 & 7)] = (bf16_t)pv;
      }
    asm volatile("s_waitcnt vmcnt(0)" ::: "memory");
    __syncthreads();
    bf16x8 pf[4];
    #pragma unroll
    for (int ksub = 0; ksub < 4; ++ksub) {
      const int g = ksub * 4 + quad;
      const int gs = (g & 8) | ((g & 7) ^ (m16 & 7));
      pf[ksub] = *(const bf16x8*)&Ps[wid][m16 * 128 + gs * 8];
    }
    #pragma unroll
    for (int dt = 0; dt < 4; ++dt) {
      const int n = dt * 16 + m16;
      #pragma unroll
      for (int ksub = 0; ksub < 4; ++ksub) {
        const int g = ksub * 4 + quad;
        const int gs = (g & 8) | ((g & 7) ^ (n & 7));
        bf16x8 vf = *(const bf16x8*)&Vs[n * 128 + gs * 8];
        oacc[dt] = __builtin_amdgcn_mfma_f32_16x16x32_bf16(pf[ksub], vf, oacc[dt], 0, 0, 0);
      }
    }
    __syncthreads();
  }
  #pragma unroll
  for (int r = 0; r < 4; ++r) {
    rs[r] += __shfl_xor(rs[r], 1);
    rs[r] += __shfl_xor(rs[r], 2);
    rs[r] += __shfl_xor(rs[r], 4);
    rs[r] += __shfl_xor(rs[r], 8);
  }
  const size_t obase = ((size_t)(b * 1024 + qt * 64 + wid * 16)) * 1024 + h * 64;
  #pragma unroll
  for (int dt = 0; dt < 4; ++dt)
    #pragma unroll
    for (int r = 0; r < 4; ++r)
      O[obase + (size_t)(quad * 4 + r) * 1024 + dt * 16 + m16] = (bf16_t)(oacc[dt][r] / rs[r]);
}

// ---------------- segmented fp32 -> bf16 conversion (inputs stage) ----------------
struct Segs {
  const float* s[4];
  bf16_t* d[4];
  int n8[4];
};
__global__ __launch_bounds__(256)
void conv_multi(Segs sg) {
  const int zz = blockIdx.z;
  conv_f32_bf16(sg.s[zz], sg.d[zz], sg.n8[zz],
                blockIdx.x * 256 + threadIdx.x, gridDim.x * 256);
}

// ---------------- LN1 (p0+p1+resid) + fused W1 fp32->bf16 conversion ----------------
// Blocks [0,1024): LN rows. Blocks [1024,2048): conv W1 -> w1dst (vt region,
// V^T dead after attn; disjoint from LN's reads outlo/kb/xb and write outhi).
__global__ __launch_bounds__(256)
void ln_combine(const bf16_t* __restrict__ p0, const bf16_t* __restrict__ p1,
                const bf16_t* __restrict__ resid,
                const float* __restrict__ g, const float* __restrict__ b,
                bf16_t* __restrict__ out,
                const float* __restrict__ w1src, bf16_t* __restrict__ w1dst) {
  if (blockIdx.x >= 1024) {
    const int n8 = (int)((size_t)4096 * 1024 / 8);
    conv_f32_bf16(w1src, w1dst, n8, (blockIdx.x - 1024) * 256 + threadIdx.x, 1024 * 256);
    return;
  }
  const int row = blockIdx.x * 4 + (threadIdx.x >> 6);
  const int lane = threadIdx.x & 63;
  const size_t base = (size_t)row * 1024 + lane * 16;
  bf16x8 a0 = *(const bf16x8*)&p0[base];
  bf16x8 a1 = *(const bf16x8*)&p0[base + 8];
  bf16x8 b0 = *(const bf16x8*)&p1[base];
  bf16x8 b1 = *(const bf16x8*)&p1[base + 8];
  bf16x8 c0 = *(const bf16x8*)&resid[base];
  bf16x8 c1 = *(const bf16x8*)&resid[base + 8];
  float f[16];
  #pragma unroll
  for (int j = 0; j < 8; ++j) {
    f[j]     = (float)a0[j] + (float)b0[j] + (float)c0[j];
    f[8 + j] = (float)a1[j] + (float)b1[j] + (float)c1[j];
  }
  float s = 0.f, ss = 0.f;
  #pragma unroll
  for (int j = 0; j < 16; ++j) { s += f[j]; ss += f[j] * f[j]; }
  #pragma unroll
  for (int off = 1; off < 64; off <<= 1) { s += __shfl_xor(s, off); ss += __shfl_xor(ss, off); }
  const float m = s * (1.f / 1024.f);
  const float inv_sd = rsqrtf(ss * (1.f / 1024.f) - m * m + 1e-5f);
  const float* gp = g + lane * 16;
  const float* bp = b + lane * 16;
  bf16x8 o0, o1;
  #pragma unroll
  for (int j = 0; j < 8; ++j) o0[j] = (bf16_t)((f[j] - m) * inv_sd * gp[j] + bp[j]);
  #pragma unroll
  for (int j = 0; j < 8; ++j) o1[j] = (bf16_t)((f[8 + j] - m) * inv_sd * gp[8 + j] + bp[8 + j]);
  *(bf16x8*)&out[base] = o0;
  *(bf16x8*)&out[base + 8] = o1;
}

// ---- fused: (W2 combine + b2 + resid) -> LN2 -> x2; quantum -> z; ql2w conv ----
__global__ __launch_bounds__(256)
void ln2_quantum(const bf16_t* __restrict__ p0, const bf16_t* __restrict__ p1,
                 const bf16_t* __restrict__ resid, const float* __restrict__ bias,
                 const float* __restrict__ g, const float* __restrict__ b,
                 bf16_t* __restrict__ x2,
                 const float* __restrict__ qw1, const float* __restrict__ qb1,
                 const float* __restrict__ qwt, bf16_t* __restrict__ zout,
                 const float* __restrict__ ql2w, bf16_t* __restrict__ ql2wb) {
  if (blockIdx.z == 1) {
    const int n8 = 1024 * 1032 / 8;
    conv_f32_bf16(ql2w, ql2wb, n8, blockIdx.x * 256 + threadIdx.x, gridDim.x * 256);
    return;
  }
  const int row = blockIdx.x * 4 + (threadIdx.x >> 6);
  const int lane = threadIdx.x & 63;
  const size_t base = (size_t)row * 1024 + lane * 16;
  bf16x8 a0 = *(const bf16x8*)&p0[base];
  bf16x8 a1 = *(const bf16x8*)&p0[base + 8];
  bf16x8 b0 = *(const bf16x8*)&p1[base];
  bf16x8 b1 = *(const bf16x8*)&p1[base + 8];
  bf16x8 c0 = *(const bf16x8*)&resid[base];
  bf16x8 c1 = *(const bf16x8*)&resid[base + 8];
  const float* bsp = bias + lane * 16;
  float f[16];
  #pragma unroll
  for (int j = 0; j < 8; ++j) {
    f[j]     = (float)a0[j] + (float)b0[j] + (float)c0[j] + bsp[j];
    f[8 + j] = (float)a1[j] + (float)b1[j] + (float)c1[j] + bsp[8 + j];
  }
  float s = 0.f, ss = 0.f;
  #pragma unroll
  for (int j = 0; j < 16; ++j) { s += f[j]; ss += f[j] * f[j]; }
  #pragma unroll
  for (int off = 1; off < 64; off <<= 1) { s += __shfl_xor(s, off); ss += __shfl_xor(ss, off); }
  const float m = s * (1.f / 1024.f);
  const float inv_sd = rsqrtf(ss * (1.f / 1024.f) - m * m + 1e-5f);
  const float* gp = g + lane * 16;
  const float* bp = b + lane * 16;
  bf16x8 o0, o1;
  #pragma unroll
  for (int j = 0; j < 8; ++j) o0[j] = (bf16_t)((f[j] - m) * inv_sd * gp[j] + bp[j]);
  #pragma unroll
  for (int j = 0; j < 8; ++j) o1[j] = (bf16_t)((f[8 + j] - m) * inv_sd * gp[8 + j] + bp[8 + j]);
  *(bf16x8*)&x2[base] = o0;
  *(bf16x8*)&x2[base + 8] = o1;
  float th[8];
  #pragma unroll
  for (int qq = 0; qq < 8; ++qq) {
    const float* wp = qw1 + (size_t)qq * 1024 + lane * 16;
    float sdot = 0.f;
    #pragma unroll
    for (int j = 0; j < 8; ++j)
      sdot += (float)o0[j] * wp[j] + (float)o1[j] * wp[8 + j];
    #pragma unroll
    for (int off = 1; off < 64; off <<= 1) sdot += __shfl_xor(sdot, off);
    th[qq] = sdot + qb1[qq] + qwt[qq];
  }
  if (lane == 0) {
    float c[8];
    #pragma unroll
    for (int qq = 0; qq < 8; ++qq) c[qq] = cosf(th[qq]);
    float z0 = 1.f;
    #pragma unroll
    for (int u = 1; u < 8; ++u) z0 *= c[u];
    zout[(size_t)row * 8 + 0] = (bf16_t)z0;
    float pp = c[0];
    #pragma unroll
    for (int w = 1; w < 8; ++w) { pp *= c[w]; zout[(size_t)row * 8 + w] = (bf16_t)pp; }
  }
}

extern "C" void kernel_launch(void* const* d_in, const int* in_sizes, int n_in,
                              void* d_out, int out_size, void* d_ws, size_t ws_size,
                              hipStream_t stream) {
  const float* x    = (const float*)d_in[0];
  const float* Wq   = (const float*)d_in[1];
  const float* Wk   = (const float*)d_in[2];
  const float* Wv   = (const float*)d_in[3];
  const float* Wo   = (const float*)d_in[4];
  const float* ln1g = (const float*)d_in[5];
  const float* ln1b = (const float*)d_in[6];
  const float* W1   = (const float*)d_in[7];
  const float* b1   = (const float*)d_in[8];
  const float* W2   = (const float*)d_in[9];
  const float* b2   = (const float*)d_in[10];
  const float* ln2g = (const float*)d_in[11];
  const float* ln2b = (const float*)d_in[12];
  const float* qw1  = (const float*)d_in[13];
  const float* qb1  = (const float*)d_in[14];
  const float* qwt  = (const float*)d_in[15];
  const float* ql2w = (const float*)d_in[16];
  const float* ql2b = (const float*)d_in[17];
  bf16_t* ws = (bf16_t*)d_ws;

  const size_t T = (size_t)4096 * 1024;
  const size_t M1 = (size_t)1024 * 1024;
  bf16_t* outlo = (bf16_t*)d_out;
  bf16_t* outhi = outlo + T;

  bf16_t* xb    = ws;            // x bf16; resid for LN1; then W2 partial p0
  bf16_t* kb    = ws + T;        // K; Wo partial p1; then w2b; then z
  bf16_t* vt    = ws + 2 * T;    // V^T; then w1b; then W2 partial p1 / x2
  bf16_t* ff    = ws + 3 * T;    // wqkvb+wob; then FFN hidden; then ql2wb
  bf16_t* wqkvb = ff;
  bf16_t* wob   = ff + 3 * M1;
  bf16_t* w1b   = vt;
  bf16_t* w2b   = kb;
  bf16_t* ql2wb = ff;
  bf16_t* q     = outlo;
  bf16_t* o     = outhi;
  bf16_t* x1    = outhi;         // LN1 out (o dead)
  bf16_t* x2    = vt;            // LN2 out (in-place over W2 p1)
  bf16_t* z     = kb;

  {
    Segs sg;
    sg.s[0] = x;  sg.d[0] = xb;            sg.n8[0] = (int)(T / 8);
    sg.s[1] = Wq; sg.d[1] = wqkvb;         sg.n8[1] = (int)(M1 / 8);
    sg.s[2] = Wk; sg.d[2] = wqkvb + M1;    sg.n8[2] = (int)(M1 / 8);
    sg.s[3] = Wv; sg.d[3] = wqkvb + 2*M1;  sg.n8[3] = (int)(M1 / 8);
    conv_multi<<<dim3(512, 1, 4), 256, 0, stream>>>(sg);
  }
  // QKV GEMM (192 blocks) + Wo conversion on the idle 64 block-slots.
  gemm_qkv<<<256, 512, 0, stream>>>(xb, wqkvb, q, kb, vt, Wo, wob);
  attn_kernel<<<1024, 256, 0, stream>>>(q, kb, vt, o);
  // Wo split-K=2 on 128x128 tile: partials outlo (q dead) + kb (K dead).
  gemm128_sk<<<512, 256, 0, stream>>>(o, wob, outlo, kb, 1024, 1024, 1024, 32, 8);
  // LN1 (reads outlo,kb,xb; writes x1) + fused W1 conversion into vt (dead).
  ln_combine<<<2048, 256, 0, stream>>>(outlo, kb, xb, ln1g, ln1b, x1, W1, w1b);
  // W1 GEMM (reads x1, w1b; writes ff) + fused W2 conversion into kb (p1 dead,
  // w2b needed by the next launch); conv hides under the GEMM tail.
  gemm256<EPI_BIAS_RELU><<<512, 512, 0, stream>>>(x1, w1b, ff, b1, 4096, 1024, 16, 16, W2, w2b);
  // W2 split-K=2 on 128x128 tile: partials xb (x dead) + vt (w1b dead).
  gemm128_sk<<<512, 256, 0, stream>>>(ff, w2b, xb, vt, 1024, 4096, 4096, 32, 8);
  ln2_quantum<<<dim3(1024, 1, 2), 256, 0, stream>>>(
      xb, vt, x1, b2, ln2g, ln2b, x2, qw1, qb1, qwt, z, ql2w, ql2wb);
  gemm64p<<<512, 256, 0, stream>>>(x2, ql2wb, (float*)d_out, ql2b, z, ql2w);
}